// Round 3
// baseline (2776.033 us; speedup 1.0000x reference)
//
#include <hip/hip_runtime.h>
#include <hip/hip_bf16.h>
#include <math.h>

#define B_ 128
#define S_ 256
#define A_ 8
#define E_ 300
#define H_ 300
#define KPAD 320
#define GD 30      // blocks per direction
#define NB 48      // padded gate-cols per block (40 real)
#define UPB 10     // hidden units per block
#define WROW 648   // LDS row stride (ushorts) for W slice
#define NBLK 60

typedef unsigned short u16;
typedef unsigned int u32;
typedef unsigned long long u64;
typedef __attribute__((ext_vector_type(8))) short short8;
typedef __attribute__((ext_vector_type(4))) float floatx4;

#define MFMA16(a, b, c) __builtin_amdgcn_mfma_f32_16x16x32_bf16((a), (b), (c), 0, 0, 0)

// ---- workspace layout (bytes) ----
static constexpr size_t oLens = 0;                       // mem_len[128], left_len[128], asp_len[128]
static constexpr size_t oCnt  = 1536;                    // per-block flags: [dir2][30] u32 @16B spacing (960B)
static constexpr size_t oH    = 4096;                    // h panels bf16 [parity2][dir2][128][320] = 327680
static constexpr size_t oMemX = oH + 327680;             // x bf16 [dir2][128][256][320] = 41943040
static constexpr size_t oWp   = oMemX + 41943040;        // packed W bf16 [2][30][48][640] = 3686400
static constexpr size_t oBp   = oWp + 3686400;           // packed bias f32 [2][30][48] = 23040
static constexpr size_t oMemV = oBp + 23040;             // locationed memory v f32 [128][256][600] = 78643200
static constexpr size_t oIT   = oMemV + 78643200;        // i^T f32 [601][128] = 307712
static constexpr size_t oGi   = oIT + 307712;            // gi^T f32 [900][128] = 460800
static constexpr size_t oGh   = oGi + 460800;            // gh^T f32 [900][128] = 460800
static constexpr size_t oEt   = oGh + 460800;            // et^T f32 [300][128] = 153600
static constexpr size_t oSc   = oEt + 153600;            // scores f32 [128][256] = 131072
static constexpr size_t WS_NEED = oSc + 131072;          // ~126 MB

__device__ __forceinline__ u16 f2bf(float f) {
  union { float f; unsigned u; } v; v.f = f;
  unsigned r = (v.u + 0x7FFFu + ((v.u >> 16) & 1u)) >> 16;
  return (u16)r;
}
__device__ __forceinline__ float sigm(float x) { return 1.f / (1.f + __expf(-x)); }
__device__ __forceinline__ float tanh_f(float x) {
  x = fminf(15.f, fmaxf(-15.f, x));
  float e = __expf(2.f * x);
  return (e - 1.f) / (e + 1.f);
}

// ---------------- K1: lengths + zero init ----------------
__global__ __launch_bounds__(256) void init_kernel(const int* __restrict__ text,
                                                   const int* __restrict__ aspect,
                                                   const int* __restrict__ leftc,
                                                   char* __restrict__ ws) {
  const int bid = blockIdx.x, tid = threadIdx.x;
  if (bid == 0) {
    if (tid < B_) {
      int c = 0; const int* p = text + tid * S_;
      for (int s = 0; s < S_; ++s) c += (p[s] != 0);
      ((int*)(ws + oLens))[tid] = c;
    }
  } else if (bid == 1) {
    if (tid < B_) {
      int c = 0; const int* p = leftc + tid * S_;
      for (int s = 0; s < S_; ++s) c += (p[s] != 0);
      ((int*)(ws + oLens + 512))[tid] = c;
    }
  } else if (bid == 2) {
    if (tid < B_) {
      int c = 0; const int* p = aspect + tid * A_;
      for (int s = 0; s < A_; ++s) c += (p[s] != 0);
      ((int*)(ws + oLens + 1024))[tid] = c;
    }
  } else {
    const int CW = 640, HW = 327680 / 4, EW = 153600 / 4;   // flags region 1536..4096
    const int total = CW + HW + EW;
    for (int i = (bid - 3) * 256 + tid; i < total; i += 64 * 256) {
      if (i < CW)            ((unsigned*)(ws + oCnt))[i] = 0u;
      else if (i < CW + HW)  ((unsigned*)(ws + oH))[i - CW] = 0u;
      else                   ((unsigned*)(ws + oEt))[i - CW - HW] = 0u;
    }
  }
}

// ---------------- K2: weight/bias pre-pack to bf16 ----------------
__global__ __launch_bounds__(256) void pack_kernel(
    const float* __restrict__ WihF, const float* __restrict__ WhhF,
    const float* __restrict__ bihF, const float* __restrict__ bhhF,
    const float* __restrict__ WihB, const float* __restrict__ WhhB,
    const float* __restrict__ bihB, const float* __restrict__ bhhB,
    char* __restrict__ ws) {
  const int WTOT = 2 * GD * NB * 640;
  int idx = blockIdx.x * 256 + threadIdx.x;
  if (idx < WTOT) {
    int k = idx % 640;
    int n = (idx / 640) % NB;
    int bg = (idx / (640 * NB)) % GD;
    int dir = idx / (640 * NB * GD);
    float v = 0.f;
    if (n < 40) {
      int col = (n & 3) * 300 + bg * UPB + (n >> 2);  // gate*300 + unit
      const float* Wih = dir ? WihB : WihF;
      const float* Whh = dir ? WhhB : WhhF;
      if (k < 300)               v = Wih[(size_t)col * 300 + k];
      else if (k >= 320 && k < 620) v = Whh[(size_t)col * 300 + (k - 320)];
    }
    ((u16*)(ws + oWp))[idx] = f2bf(v);
  } else {
    int j = idx - WTOT;
    if (j < 2 * GD * NB) {
      int n = j % NB; int bg = (j / NB) % GD; int dir = j / (NB * GD);
      float v = 0.f;
      if (n < 40) {
        int col = (n & 3) * 300 + bg * UPB + (n >> 2);
        v = (dir ? bihB : bihF)[col] + (dir ? bhhB : bhhF)[col];
      }
      ((float*)(ws + oBp))[j] = v;
    }
  }
}

// ---------------- K3: embedding gather (bwd dir pre-reversed) ----------------
__global__ __launch_bounds__(KPAD) void gather_kernel(const int* __restrict__ text,
                                                      const float* __restrict__ emb,
                                                      char* __restrict__ ws) {
  const int bid = blockIdx.x;
  const int t = bid & 255;
  const int b = (bid >> 8) & 127;
  const int dir = bid >> 15;
  const int len = ((const int*)(ws + oLens))[b];
  const int tp = (dir == 0) ? t : ((t < len) ? (len - 1 - t) : t);
  const int tok = text[b * S_ + tp];
  u16* dst = (u16*)(ws + oMemX) + ((size_t)((dir * B_ + b) * S_ + t)) * KPAD;
  const float* src = emb + (size_t)tok * E_;
  const int k = threadIdx.x;
  float v = (k < E_) ? src[k] : 0.f;
  dst[k] = f2bf(v);
}

// ---------------- K4: persistent BiLSTM ----------------
// Cross-block h exchange via RELAXED agent-scope (sc1, L3-coherent) atomics.
// All global loads are BATCH-ISSUED into registers before their consumers so
// each section costs ~1 RTT instead of N serialized RTTs.
__global__ __launch_bounds__(512, 1) void lstm_kernel(char* __restrict__ ws) {
  const int dir = (int)blockIdx.x / GD;
  const int bg  = (int)blockIdx.x % GD;
  const int tid = threadIdx.x;
  const int wv = tid >> 6;
  const int lane = tid & 63;
  const int quad = lane >> 4;
  const int l16 = lane & 15;

  const u16* __restrict__ Wp = (const u16*)(ws + oWp) + (size_t)(dir * GD + bg) * NB * 640;
  const float* __restrict__ Bpk = (const float*)(ws + oBp) + (dir * GD + bg) * NB;
  const u16* __restrict__ memx = (const u16*)(ws + oMemX) + (size_t)dir * B_ * S_ * KPAD;
  u64* __restrict__ hb64 = (u64*)(ws + oH);
  u32* __restrict__ hb32 = (u32*)(ws + oH);
  float* __restrict__ memv = (float*)(ws + oMemV);
  const int* __restrict__ mlen = (const int*)(ws + oLens);
  const int* __restrict__ llen = (const int*)(ws + oLens + 512);
  const int* __restrict__ alen = (const int*)(ws + oLens + 1024);
  u32* __restrict__ flags = (u32*)(ws + oCnt) + (size_t)dir * 120;  // 30 slots, 16B apart

  __shared__ __align__(16) u16 Wlds[NB * WROW];
  __shared__ float gatesLds[128 * 49];
  __shared__ float cS[1280];
  __shared__ float hS[1280];
  __shared__ float biasS[NB];
  __shared__ int lenS[128], llS[128], alS[128];

  for (int i = tid; i < NB * 640; i += 512) {
    int n = i / 640;
    Wlds[n * WROW + (i - n * 640)] = Wp[i];
  }
  for (int i = tid; i < 1280; i += 512) { cS[i] = 0.f; hS[i] = 0.f; }
  if (tid < NB) biasS[tid] = Bpk[tid];
  if (tid < 128) { lenS[tid] = mlen[tid]; llS[tid] = llen[tid]; alS[tid] = alen[tid]; }
  __syncthreads();

  const int row = wv * 16 + l16;  // batch row this lane covers in A-frags
  const u16* wbase = Wlds + l16 * WROW + quad * 8;

  // preload x fragments for t = 0
  short8 xv[10];
  {
    const u16* xr = memx + ((size_t)row * S_) * KPAD + quad * 8;
    #pragma unroll
    for (int kk = 0; kk < 10; ++kk) xv[kk] = *(const short8*)(xr + kk * 32);
  }

  for (int t = 0; t < S_; ++t) {
    if (t > 0) {
      if (wv == 0) {  // single polling wave: lanes 0..29 each watch one flag
        const u32 target = (u32)t;
        u32 f;
        do {
          f = 0xFFFFFFFFu;
          if (lane < GD)
            f = __hip_atomic_load(&flags[lane * 4], __ATOMIC_RELAXED, __HIP_MEMORY_SCOPE_AGENT);
        } while (!__all((int)(f >= target)));
      }
      __syncthreads();
      __builtin_amdgcn_fence(__ATOMIC_ACQUIRE, "workgroup");  // compiler ordering only
    }

    // batch-issue all 20 h loads (sc1) into registers
    u64 hq[20];
    {
      const u64* hbase = hb64 + (((size_t)(t & 1) * 2 + dir) * B_ + row) * 80 + quad * 2;
      #pragma unroll
      for (int kk = 0; kk < 10; ++kk) {
        hq[2 * kk]     = __hip_atomic_load(hbase + kk * 8,     __ATOMIC_RELAXED, __HIP_MEMORY_SCOPE_AGENT);
        hq[2 * kk + 1] = __hip_atomic_load(hbase + kk * 8 + 1, __ATOMIC_RELAXED, __HIP_MEMORY_SCOPE_AGENT);
      }
    }
    __builtin_amdgcn_sched_barrier(0);  // keep h-load issue above the MFMA stream

    floatx4 acc0 = {0.f, 0.f, 0.f, 0.f}, acc1 = acc0, acc2 = acc0;
    // x-part (registers ready) — hides the h-load RTT
    #pragma unroll
    for (int kk = 0; kk < 10; ++kk) {
      const int ko = kk * 32;
      acc0 = MFMA16(xv[kk], *(const short8*)(wbase + ko), acc0);
      acc1 = MFMA16(xv[kk], *(const short8*)(wbase + 16 * WROW + ko), acc1);
      acc2 = MFMA16(xv[kk], *(const short8*)(wbase + 32 * WROW + ko), acc2);
    }
    // h-part
    #pragma unroll
    for (int kk = 0; kk < 10; ++kk) {
      union { u64 q[2]; short8 v; } a;
      a.q[0] = hq[2 * kk]; a.q[1] = hq[2 * kk + 1];
      const int ko = 320 + kk * 32;
      acc0 = MFMA16(a.v, *(const short8*)(wbase + ko), acc0);
      acc1 = MFMA16(a.v, *(const short8*)(wbase + 16 * WROW + ko), acc1);
      acc2 = MFMA16(a.v, *(const short8*)(wbase + 32 * WROW + ko), acc2);
    }

    // stage gate pre-activations to LDS  (C layout: col=lane&15, row=quad*4+reg)
    {
      const int rbase = wv * 16 + quad * 4;
      #pragma unroll
      for (int r = 0; r < 4; ++r) {
        gatesLds[(rbase + r) * 49 + l16] = acc0[r];
        gatesLds[(rbase + r) * 49 + 16 + l16] = acc1[r];
        gatesLds[(rbase + r) * 49 + 32 + l16] = acc2[r];
      }
    }
    __syncthreads();

    // elementwise LSTM cell; h stores now, memv stores deferred past the drain
    const int nxt = (t + 1) & 1;
    float2 sv[2]; float* sa[2];
    #pragma unroll
    for (int z = 0; z < 2; ++z) {
      const int it = tid + z * 512;
      if (z == 1 && tid >= 128) break;
      const int b = it / 5;
      const int pl = it - b * 5;
      const int u0 = pl * 2;
      const int len = lenS[b];
      const bool m = (t < len);
      const float* gp = gatesLds + b * 49 + u0 * 4;
      const float* bp = biasS + u0 * 4;
      float h0K, h1K, h0N, h1N;
      {
        float ig = sigm(gp[0] + bp[0]);
        float fg = sigm(gp[1] + bp[1]);
        float gt = tanh_f(gp[2] + bp[2]);
        float og = sigm(gp[3] + bp[3]);
        float cOld = cS[b * 10 + u0], hOld = hS[b * 10 + u0];
        float cNew = fg * cOld + ig * gt;
        float hNew = og * tanh_f(cNew);
        cS[b * 10 + u0] = m ? cNew : cOld;
        h0K = m ? hNew : hOld;
        hS[b * 10 + u0] = h0K;
        h0N = m ? hNew : 0.f;
      }
      {
        float ig = sigm(gp[4] + bp[4]);
        float fg = sigm(gp[5] + bp[5]);
        float gt = tanh_f(gp[6] + bp[6]);
        float og = sigm(gp[7] + bp[7]);
        float cOld = cS[b * 10 + u0 + 1], hOld = hS[b * 10 + u0 + 1];
        float cNew = fg * cOld + ig * gt;
        float hNew = og * tanh_f(cNew);
        cS[b * 10 + u0 + 1] = m ? cNew : cOld;
        h1K = m ? hNew : hOld;
        hS[b * 10 + u0 + 1] = h1K;
        h1N = m ? hNew : 0.f;
      }
      u32 packed = (u32)f2bf(h0K) | ((u32)f2bf(h1K) << 16);
      __hip_atomic_store(&hb32[(((size_t)nxt * 2 + dir) * B_ + b) * 160 + bg * 5 + pl],
                         packed, __ATOMIC_RELAXED, __HIP_MEMORY_SCOPE_AGENT);
      int pos = (dir == 0) ? t : (m ? (len - 1 - t) : t);
      float ml = (float)len, ll = (float)llS[b], al = (float)alS[b];
      float p = (float)pos;
      float wl;
      if (p < ll) wl = 1.f - (ll - p) / ml;
      else if ((p >= ll + al) && (p < ml)) wl = 1.f - (p - ll - al + 1.f) / ml;
      else wl = 1.f;
      sv[z] = make_float2(h0N * wl, h1N * wl);
      sa[z] = &memv[((size_t)b * S_ + pos) * 600 + dir * 300 + bg * UPB + u0];
    }

    __builtin_amdgcn_fence(__ATOMIC_RELEASE, "workgroup");
    __syncthreads();  // per-wave vmcnt(0) drain: h stores are at the coherence point
    if (tid == 0)
      __hip_atomic_store(&flags[bg * 4], (u32)(t + 1), __ATOMIC_RELAXED, __HIP_MEMORY_SCOPE_AGENT);

    // deferred memv stores + next-step x prefetch — overlap the next poll window
    *(float2*)sa[0] = sv[0];
    if (tid < 128) *(float2*)sa[1] = sv[1];
    if (t + 1 < S_) {
      const u16* xr = memx + ((size_t)row * S_ + (t + 1)) * KPAD + quad * 8;
      #pragma unroll
      for (int kk = 0; kk < 10; ++kk) xv[kk] = *(const short8*)(xr + kk * 32);
    }
  }
}

// ---------------- K5: attention scores ----------------
__global__ __launch_bounds__(256) void score_kernel(const float* __restrict__ attW,
                                                    char* __restrict__ ws) {
  const int bid = blockIdx.x;
  const int b = bid >> 1, sh = bid & 1;
  const int tid = threadIdx.x, wv = tid >> 6, lane = tid & 63;
  __shared__ float aW[601];
  for (int i = tid; i < 601; i += 256) aW[i] = attW[i];
  const float* memv = (const float*)(ws + oMemV) + (size_t)b * S_ * 600;
  const float ml = (float)((const int*)(ws + oLens))[b];
  const float ll = (float)((const int*)(ws + oLens + 512))[b];
  const float al = (float)((const int*)(ws + oLens + 1024))[b];
  __syncthreads();
  float* scg = (float*)(ws + oSc) + b * S_;
  for (int s = sh * 128 + wv; s < sh * 128 + 128; s += 4) {
    const float* rowp = memv + (size_t)s * 600;
    float acc = 0.f;
    for (int d = lane; d < 600; d += 64) acc += rowp[d] * aW[d];
    for (int off = 32; off; off >>= 1) acc += __shfl_xor(acc, off);
    if (lane == 0) {
      float p = (float)s;
      bool inl = p < ll;
      bool inr = (p >= ll + al) && (p < ml);
      float u = inl ? (p - ll) : (inr ? (p - ll - al + 1.f) : 0.f);
      scg[s] = acc + u * aW[600];
    }
  }
}

// ---------------- K6: softmax + weighted sum -> i^T ----------------
__global__ __launch_bounds__(256) void attn_kernel(char* __restrict__ ws) {
  const int bid = blockIdx.x;
  const int b = bid >> 1, dh = bid & 1;
  const int tid = threadIdx.x, wv = tid >> 6, lane = tid & 63;
  __shared__ float alpha[256];
  __shared__ float red[8];
  const float* scg = (const float*)(ws + oSc) + b * S_;
  float v = scg[tid];
  float mx = v;
  for (int off = 32; off; off >>= 1) mx = fmaxf(mx, __shfl_xor(mx, off));
  if (lane == 0) red[wv] = mx;
  __syncthreads();
  mx = fmaxf(fmaxf(red[0], red[1]), fmaxf(red[2], red[3]));
  float e = __expf(v - mx);
  float sm = e;
  for (int off = 32; off; off >>= 1) sm += __shfl_xor(sm, off);
  if (lane == 0) red[4 + wv] = sm;
  __syncthreads();
  float tot = red[4] + red[5] + red[6] + red[7];
  alpha[tid] = e / tot;
  const float ml = (float)((const int*)(ws + oLens))[b];
  const float ll = (float)((const int*)(ws + oLens + 512))[b];
  const float al = (float)((const int*)(ws + oLens + 1024))[b];
  __syncthreads();
  const float* memv = (const float*)(ws + oMemV) + (size_t)b * S_ * 600;
  float* iT = (float*)(ws + oIT);
  const int d0 = dh * 301, d1 = dh ? 601 : 301;
  for (int d = d0 + tid; d < d1; d += 256) {
    float acc = 0.f;
    if (d < 600) {
      for (int s = 0; s < 256; ++s) acc += alpha[s] * memv[(size_t)s * 600 + d];
    } else {
      for (int s = 0; s < 256; ++s) {
        float p = (float)s;
        bool inl = p < ll;
        bool inr = (p >= ll + al) && (p < ml);
        float u = inl ? (p - ll) : (inr ? (p - ll - al + 1.f) : 0.f);
        acc += alpha[s] * u;
      }
    }
    iT[d * 128 + b] = acc;
  }
}

// ---------------- K7: GRU gi (once) ----------------
__global__ __launch_bounds__(256) void gi_kernel(const float* __restrict__ Wih,
                                                 const float* __restrict__ bih,
                                                 char* __restrict__ ws) {
  int idx = blockIdx.x * 256 + threadIdx.x;
  int r = idx >> 7, b = idx & 127;
  if (r >= 900) return;
  const float* iT = (const float*)(ws + oIT);
  const float* wr = Wih + (size_t)r * 601;
  float acc = bih[r];
  for (int d = 0; d < 601; ++d) acc += iT[d * 128 + b] * wr[d];
  ((float*)(ws + oGi))[r * 128 + b] = acc;
}

// ---------------- K8: GRU gh (per hop) ----------------
__global__ __launch_bounds__(256) void gh_kernel(const float* __restrict__ Whh,
                                                 const float* __restrict__ bhh,
                                                 char* __restrict__ ws) {
  int idx = blockIdx.x * 256 + threadIdx.x;
  int r = idx >> 7, b = idx & 127;
  if (r >= 900) return;
  const float* et = (const float*)(ws + oEt);
  const float* wr = Whh + (size_t)r * 300;
  float acc = bhh[r];
  for (int u = 0; u < 300; ++u) acc += et[u * 128 + b] * wr[u];
  ((float*)(ws + oGh))[r * 128 + b] = acc;
}

// ---------------- K9: GRU update (per hop) ----------------
__global__ __launch_bounds__(256) void up_kernel(char* __restrict__ ws) {
  int idx = blockIdx.x * 256 + threadIdx.x;
  int u = idx >> 7, b = idx & 127;
  if (u >= 300) return;
  const float* gi = (const float*)(ws + oGi);
  const float* gh = (const float*)(ws + oGh);
  float* et = (float*)(ws + oEt);
  float rr = sigm(gi[u * 128 + b] + gh[u * 128 + b]);
  float zz = sigm(gi[(300 + u) * 128 + b] + gh[(300 + u) * 128 + b]);
  float nn = tanh_f(gi[(600 + u) * 128 + b] + rr * gh[(600 + u) * 128 + b]);
  float old = et[u * 128 + b];
  et[u * 128 + b] = (1.f - zz) * nn + zz * old;
}

// ---------------- K10: dense head ----------------
__global__ __launch_bounds__(384) void dense_kernel(const float* __restrict__ dW,
                                                    const float* __restrict__ dB,
                                                    float* __restrict__ out,
                                                    const char* __restrict__ ws) {
  int tid = threadIdx.x;
  if (tid >= 384) return;
  int b = tid / 3, c = tid - 3 * (tid / 3);
  const float* et = (const float*)(ws + oEt);
  float acc = dB[c];
  const float* wr = dW + c * 300;
  for (int u = 0; u < 300; ++u) acc += et[u * 128 + b] * wr[u];
  out[b * 3 + c] = acc;
}

extern "C" void kernel_launch(void* const* d_in, const int* in_sizes, int n_in,
                              void* d_out, int out_size, void* d_ws, size_t ws_size,
                              hipStream_t stream) {
  const int* text = (const int*)d_in[0];
  const int* aspect = (const int*)d_in[1];
  const int* leftc = (const int*)d_in[2];
  const float* emb = (const float*)d_in[3];
  const float* WihF = (const float*)d_in[4];
  const float* WhhF = (const float*)d_in[5];
  const float* bihF = (const float*)d_in[6];
  const float* bhhF = (const float*)d_in[7];
  const float* WihB = (const float*)d_in[8];
  const float* WhhB = (const float*)d_in[9];
  const float* bihB = (const float*)d_in[10];
  const float* bhhB = (const float*)d_in[11];
  const float* attW = (const float*)d_in[12];
  const float* gruWih = (const float*)d_in[14];
  const float* gruWhh = (const float*)d_in[15];
  const float* gruBih = (const float*)d_in[16];
  const float* gruBhh = (const float*)d_in[17];
  const float* denseW = (const float*)d_in[18];
  const float* denseB = (const float*)d_in[19];
  float* out = (float*)d_out;
  char* ws = (char*)d_ws;
  if (ws_size < WS_NEED) return;

  init_kernel<<<67, 256, 0, stream>>>(text, aspect, leftc, ws);
  pack_kernel<<<7212, 256, 0, stream>>>(WihF, WhhF, bihF, bhhF, WihB, WhhB, bihB, bhhB, ws);
  gather_kernel<<<2 * B_ * S_, KPAD, 0, stream>>>(text, emb, ws);
  lstm_kernel<<<NBLK, 512, 0, stream>>>(ws);
  score_kernel<<<2 * B_, 256, 0, stream>>>(attW, ws);
  attn_kernel<<<2 * B_, 256, 0, stream>>>(ws);
  gi_kernel<<<450, 256, 0, stream>>>(gruWih, gruBih, ws);
  for (int h = 0; h < 3; ++h) {
    gh_kernel<<<450, 256, 0, stream>>>(gruWhh, gruBhh, ws);
    up_kernel<<<150, 256, 0, stream>>>(ws);
  }
  dense_kernel<<<1, 384, 0, stream>>>(denseW, denseB, out, ws);
}

// Round 5
// 2320.120 us; speedup vs baseline: 1.1965x; 1.1965x over previous
//
#include <hip/hip_runtime.h>
#include <hip/hip_bf16.h>
#include <math.h>

#define B_ 128
#define S_ 256
#define A_ 8
#define E_ 300
#define H_ 300
#define KPAD 320
#define NGU 16     // unit groups per direction
#define NGB 4      // batch groups (32 rows each)
#define NCOL 80    // padded gate-cols per unit group (<=80 real)
#define WROW 648   // LDS row stride (u16) for W slice rows
#define NBLK 128   // 2 dir * 4 gb * 16 gu

typedef unsigned short u16;
typedef unsigned int u32;
typedef unsigned long long u64;
typedef __attribute__((ext_vector_type(8))) short short8;
typedef __attribute__((ext_vector_type(4))) float floatx4;

#define MFMA16(a, b, c) __builtin_amdgcn_mfma_f32_16x16x32_bf16((a), (b), (c), 0, 0, 0)

__device__ __host__ __forceinline__ int gu_cnt(int g) { return g < 6 ? 20 : 18; }
__device__ __host__ __forceinline__ int gu_u0(int g) { return g < 6 ? 20 * g : 120 + 18 * (g - 6); }

// ---- workspace layout (bytes) ----
static constexpr size_t oLens = 0;                       // mem_len[128], left_len[128], asp_len[128]
static constexpr size_t oFlg  = 1536;                    // flags [dir2][gb4][gu16] @16B spacing (2048B)
static constexpr size_t oH    = 4096;                    // h bf16 [parity2][dir2][128][320] = 327680
static constexpr size_t oMemX = 331776;                  // x bf16 [dir2][128][256][320] = 41943040
static constexpr size_t oWp   = 42274816;                // packed W bf16 [2][16][80][640] = 3276800
static constexpr size_t oBp   = 45551616;                // packed bias f32 [2][16][80] = 10240
static constexpr size_t oMemV = 45561856;                // locationed memory v f32 [128][256][600] = 78643200
static constexpr size_t oIT   = 124205056;               // i^T f32 [601][128]
static constexpr size_t oGi   = 124512768;               // gi^T f32 [900][128]
static constexpr size_t oGh   = 124973568;               // gh^T f32 [900][128]
static constexpr size_t oEt   = 125434368;               // et^T f32 [300][128]
static constexpr size_t oSc   = 125587968;               // scores f32 [128][256]
static constexpr size_t WS_NEED = 125719040;             // ~120 MB

__device__ __forceinline__ u16 f2bf(float f) {
  union { float f; unsigned u; } v; v.f = f;
  unsigned r = (v.u + 0x7FFFu + ((v.u >> 16) & 1u)) >> 16;
  return (u16)r;
}
__device__ __forceinline__ float sigm(float x) { return 1.f / (1.f + __expf(-x)); }
__device__ __forceinline__ float tanh_f(float x) {
  x = fminf(15.f, fmaxf(-15.f, x));
  float e = __expf(2.f * x);
  return (e - 1.f) / (e + 1.f);
}

// ---------------- K1: lengths + zero init ----------------
__global__ __launch_bounds__(256) void init_kernel(const int* __restrict__ text,
                                                   const int* __restrict__ aspect,
                                                   const int* __restrict__ leftc,
                                                   char* __restrict__ ws) {
  const int bid = blockIdx.x, tid = threadIdx.x;
  if (bid == 0) {
    if (tid < B_) {
      int c = 0; const int* p = text + tid * S_;
      for (int s = 0; s < S_; ++s) c += (p[s] != 0);
      ((int*)(ws + oLens))[tid] = c;
    }
  } else if (bid == 1) {
    if (tid < B_) {
      int c = 0; const int* p = leftc + tid * S_;
      for (int s = 0; s < S_; ++s) c += (p[s] != 0);
      ((int*)(ws + oLens + 512))[tid] = c;
    }
  } else if (bid == 2) {
    if (tid < B_) {
      int c = 0; const int* p = aspect + tid * A_;
      for (int s = 0; s < A_; ++s) c += (p[s] != 0);
      ((int*)(ws + oLens + 1024))[tid] = c;
    }
  } else {
    const int CW = 640, HW = 327680 / 4, EW = 153600 / 4;
    const int total = CW + HW + EW;
    for (int i = (bid - 3) * 256 + tid; i < total; i += 64 * 256) {
      if (i < CW)            ((unsigned*)(ws + oFlg))[i] = 0u;
      else if (i < CW + HW)  ((unsigned*)(ws + oH))[i - CW] = 0u;
      else                   ((unsigned*)(ws + oEt))[i - CW - HW] = 0u;
    }
  }
}

// ---------------- K2: weight/bias pre-pack to bf16 ----------------
// Wp layout: [dir2][gu16][col80][k640]; col n -> unit_local=n>>2, gate=n&3;
// k<300: Wih, 320<=k<620: Whh, else 0.
__global__ __launch_bounds__(256) void pack_kernel(
    const float* __restrict__ WihF, const float* __restrict__ WhhF,
    const float* __restrict__ bihF, const float* __restrict__ bhhF,
    const float* __restrict__ WihB, const float* __restrict__ WhhB,
    const float* __restrict__ bihB, const float* __restrict__ bhhB,
    char* __restrict__ ws) {
  const int WTOT = 2 * NGU * NCOL * 640;
  int idx = blockIdx.x * 256 + threadIdx.x;
  if (idx < WTOT) {
    int k = idx % 640;
    int n = (idx / 640) % NCOL;
    int g = (idx / (640 * NCOL)) % NGU;
    int dir = idx / (640 * NCOL * NGU);
    float v = 0.f;
    const int cnt = gu_cnt(g), u0 = gu_u0(g);
    if (n < cnt * 4) {
      int col = (n & 3) * 300 + u0 + (n >> 2);
      const float* Wih = dir ? WihB : WihF;
      const float* Whh = dir ? WhhB : WhhF;
      if (k < 300)                  v = Wih[(size_t)col * 300 + k];
      else if (k >= 320 && k < 620) v = Whh[(size_t)col * 300 + (k - 320)];
    }
    ((u16*)(ws + oWp))[idx] = f2bf(v);
  } else {
    int j = idx - WTOT;
    if (j < 2 * NGU * NCOL) {
      int n = j % NCOL; int g = (j / NCOL) % NGU; int dir = j / (NCOL * NGU);
      float v = 0.f;
      const int cnt = gu_cnt(g), u0 = gu_u0(g);
      if (n < cnt * 4) {
        int col = (n & 3) * 300 + u0 + (n >> 2);
        v = (dir ? bihB : bihF)[col] + (dir ? bhhB : bhhF)[col];
      }
      ((float*)(ws + oBp))[j] = v;
    }
  }
}

// ---------------- K3: embedding gather (bwd dir pre-reversed) ----------------
__global__ __launch_bounds__(KPAD) void gather_kernel(const int* __restrict__ text,
                                                      const float* __restrict__ emb,
                                                      char* __restrict__ ws) {
  const int bid = blockIdx.x;
  const int t = bid & 255;
  const int b = (bid >> 8) & 127;
  const int dir = bid >> 15;
  const int len = ((const int*)(ws + oLens))[b];
  const int tp = (dir == 0) ? t : ((t < len) ? (len - 1 - t) : t);
  const int tok = text[b * S_ + tp];
  u16* dst = (u16*)(ws + oMemX) + ((size_t)((dir * B_ + b) * S_ + t)) * KPAD;
  const float* src = emb + (size_t)tok * E_;
  const int k = threadIdx.x;
  float v = (k < E_) ? src[k] : 0.f;
  dst[k] = f2bf(v);
}

// ---------------- K4: persistent BiLSTM ----------------
// Grid 128 = [dir2][gb4][gu16]; each block: 32 batch rows x ~18-20 hidden units.
// Exchange pods = 16 blocks sharing a (dir,gb); h via relaxed agent (sc1) atomics.
// Per-block per-step global traffic ~20KB h + ~40KB x (vs 160KB before).
__global__ __launch_bounds__(256, 1) void lstm_kernel(char* __restrict__ ws) {
  const int bid = (int)blockIdx.x;
  const int dir = bid >> 6;
  const int gb  = (bid >> 4) & 3;
  const int g   = bid & 15;
  const int cnt = gu_cnt(g), u0 = gu_u0(g);
  const int npair = cnt >> 1;           // 10 or 9
  const int tid = threadIdx.x;
  const int wv = tid >> 6;              // 0..3
  const int lane = tid & 63;
  const int quad = lane >> 4;
  const int l16 = lane & 15;
  const int Mtile = wv >> 1;            // 0/1 -> rows [Mtile*16, +16)
  const int nt0 = (wv & 1) ? 3 : 0;     // Ntile set {0,1,2} or {3,4}
  const int ntc = (wv & 1) ? 2 : 3;

  const u64* __restrict__ Wp64 = (const u64*)(ws + oWp) + (size_t)(dir * NGU + g) * NCOL * 160;
  const float* __restrict__ Bpk = (const float*)(ws + oBp) + (dir * NGU + g) * NCOL;
  const u16* __restrict__ memx = (const u16*)(ws + oMemX) + (size_t)dir * B_ * S_ * KPAD;
  u64* __restrict__ hb64 = (u64*)(ws + oH);
  u32* __restrict__ hb32 = (u32*)(ws + oH);
  float* __restrict__ memv = (float*)(ws + oMemV);
  u32* __restrict__ flags = (u32*)(ws + oFlg) + (size_t)(dir * 4 + gb) * 64;  // 16 slots @16B

  __shared__ __align__(16) u16 Wlds[NCOL * WROW];          // 103680 B
  __shared__ float gatesLds[32 * 81];                      // 10368 B
  __shared__ float cS[640];
  __shared__ float hS[640];
  __shared__ float biasS[NCOL];
  __shared__ int lenS[32], llS[32], alS[32];

  // load W slice: global [n][640] u16 -> LDS [n][WROW]
  for (int i = tid; i < NCOL * 160; i += 256) {
    int n = i / 160, k4 = i - n * 160;
    ((u64*)Wlds)[n * 162 + k4] = Wp64[i];
  }
  for (int i = tid; i < 640; i += 256) { cS[i] = 0.f; hS[i] = 0.f; }
  if (tid < NCOL) biasS[tid] = Bpk[tid];
  if (tid < 32) {
    lenS[tid] = ((const int*)(ws + oLens))[gb * 32 + tid];
    llS[tid]  = ((const int*)(ws + oLens + 512))[gb * 32 + tid];
    alS[tid]  = ((const int*)(ws + oLens + 1024))[gb * 32 + tid];
  }
  __syncthreads();

  const int row = gb * 32 + Mtile * 16 + l16;   // global batch row for A-frags
  // B-operand base: column n = ntile*16 + l16 lives at Wlds[n*WROW + k].
  // (R4 bug: the l16*WROW term was missing -> every lane read its tile-base column.)
  const u16* wq = Wlds + l16 * WROW + quad * 8;

  // prefetch x fragments for t = 0
  short8 xv[10];
  {
    const u16* xr = memx + ((size_t)row * S_) * KPAD + quad * 8;
    #pragma unroll
    for (int kk = 0; kk < 10; ++kk) xv[kk] = *(const short8*)(xr + kk * 32);
  }

  for (int t = 0; t < S_; ++t) {
    if (t > 0) {
      if (wv == 0) {
        const u32 target = (u32)t;
        u32 f;
        do {
          f = 0xFFFFFFFFu;
          if (lane < NGU)
            f = __hip_atomic_load(&flags[lane * 4], __ATOMIC_RELAXED, __HIP_MEMORY_SCOPE_AGENT);
        } while (!__all((int)(f >= target)));
      }
      __syncthreads();
      __builtin_amdgcn_fence(__ATOMIC_ACQUIRE, "workgroup");
    }

    // batch-issue the 20 h-loads (sc1) for this wave's 16 rows
    u64 hq[20];
    {
      const u64* hbase = hb64 + (((size_t)(t & 1) * 2 + dir) * B_ + row) * 80 + quad * 2;
      #pragma unroll
      for (int kk = 0; kk < 10; ++kk) {
        hq[2 * kk]     = __hip_atomic_load(hbase + kk * 8,     __ATOMIC_RELAXED, __HIP_MEMORY_SCOPE_AGENT);
        hq[2 * kk + 1] = __hip_atomic_load(hbase + kk * 8 + 1, __ATOMIC_RELAXED, __HIP_MEMORY_SCOPE_AGENT);
      }
    }
    __builtin_amdgcn_sched_barrier(0);

    floatx4 acc[3];
    acc[0] = (floatx4){0.f, 0.f, 0.f, 0.f}; acc[1] = acc[0]; acc[2] = acc[0];
    // x-part (prefetched regs) — hides the h-load RTT
    #pragma unroll
    for (int kk = 0; kk < 10; ++kk) {
      const int ko = kk * 32;
      #pragma unroll
      for (int j = 0; j < 3; ++j) {
        if (j < ntc)
          acc[j] = MFMA16(xv[kk], *(const short8*)(wq + (nt0 + j) * 16 * WROW + ko), acc[j]);
      }
    }
    // h-part
    #pragma unroll
    for (int kk = 0; kk < 10; ++kk) {
      union { u64 q[2]; short8 v; } a;
      a.q[0] = hq[2 * kk]; a.q[1] = hq[2 * kk + 1];
      const int ko = 320 + kk * 32;
      #pragma unroll
      for (int j = 0; j < 3; ++j) {
        if (j < ntc)
          acc[j] = MFMA16(a.v, *(const short8*)(wq + (nt0 + j) * 16 * WROW + ko), acc[j]);
      }
    }

    // stage gates to LDS (C layout: col=lane&15, row=quad*4+reg)
    #pragma unroll
    for (int j = 0; j < 3; ++j) {
      if (j < ntc) {
        const int colb = (nt0 + j) * 16 + l16;
        const int rb = Mtile * 16 + quad * 4;
        #pragma unroll
        for (int r = 0; r < 4; ++r)
          gatesLds[(rb + r) * 81 + colb] = acc[j][r];
      }
    }
    __syncthreads();

    // elementwise LSTM cell: items = 32 rows * npair unit-pairs (<=320)
    const int nxt = (t + 1) & 1;
    float2 sv[2]; float* sa[2]; bool sval[2];
    #pragma unroll
    for (int z = 0; z < 2; ++z) {
      const int it = tid + z * 256;
      sval[z] = (it < 32 * npair);
      if (!sval[z]) continue;
      const int bl = it & 31;
      const int pl = it >> 5;
      const int ul0 = pl * 2;
      const int len = lenS[bl];
      const bool m = (t < len);
      const float* gp = gatesLds + bl * 81 + ul0 * 4;
      const float* bp = biasS + ul0 * 4;
      float h0K, h1K, h0N, h1N;
      {
        float ig = sigm(gp[0] + bp[0]);
        float fg = sigm(gp[1] + bp[1]);
        float gt = tanh_f(gp[2] + bp[2]);
        float og = sigm(gp[3] + bp[3]);
        float cOld = cS[ul0 * 32 + bl], hOld = hS[ul0 * 32 + bl];
        float cNew = fg * cOld + ig * gt;
        float hNew = og * tanh_f(cNew);
        cS[ul0 * 32 + bl] = m ? cNew : cOld;
        h0K = m ? hNew : hOld;
        hS[ul0 * 32 + bl] = h0K;
        h0N = m ? hNew : 0.f;
      }
      {
        float ig = sigm(gp[4] + bp[4]);
        float fg = sigm(gp[5] + bp[5]);
        float gt = tanh_f(gp[6] + bp[6]);
        float og = sigm(gp[7] + bp[7]);
        float cOld = cS[(ul0 + 1) * 32 + bl], hOld = hS[(ul0 + 1) * 32 + bl];
        float cNew = fg * cOld + ig * gt;
        float hNew = og * tanh_f(cNew);
        cS[(ul0 + 1) * 32 + bl] = m ? cNew : cOld;
        h1K = m ? hNew : hOld;
        hS[(ul0 + 1) * 32 + bl] = h1K;
        h1N = m ? hNew : 0.f;
      }
      const int bglob = gb * 32 + bl;
      u32 packed = (u32)f2bf(h0K) | ((u32)f2bf(h1K) << 16);
      __hip_atomic_store(&hb32[(((size_t)nxt * 2 + dir) * B_ + bglob) * 160 + ((u0 + ul0) >> 1)],
                         packed, __ATOMIC_RELAXED, __HIP_MEMORY_SCOPE_AGENT);
      int pos = (dir == 0) ? t : (m ? (len - 1 - t) : t);
      float ml = (float)len, ll = (float)llS[bl], al = (float)alS[bl];
      float p = (float)pos;
      float wl;
      if (p < ll) wl = 1.f - (ll - p) / ml;
      else if ((p >= ll + al) && (p < ml)) wl = 1.f - (p - ll - al + 1.f) / ml;
      else wl = 1.f;
      sv[z] = make_float2(h0N * wl, h1N * wl);
      sa[z] = &memv[((size_t)bglob * S_ + pos) * 600 + dir * 300 + u0 + ul0];
    }

    __builtin_amdgcn_fence(__ATOMIC_RELEASE, "workgroup");
    __syncthreads();  // drains vmcnt(0): h stores are at the coherence point
    if (tid == 0)
      __hip_atomic_store(&flags[g * 4], (u32)(t + 1), __ATOMIC_RELAXED, __HIP_MEMORY_SCOPE_AGENT);

    // deferred memv stores + next-step x prefetch — overlap the poll window
    #pragma unroll
    for (int z = 0; z < 2; ++z)
      if (sval[z]) *(float2*)sa[z] = sv[z];
    if (t + 1 < S_) {
      const u16* xr = memx + ((size_t)row * S_ + (t + 1)) * KPAD + quad * 8;
      #pragma unroll
      for (int kk = 0; kk < 10; ++kk) xv[kk] = *(const short8*)(xr + kk * 32);
    }
  }
}

// ---------------- K5: attention scores ----------------
__global__ __launch_bounds__(256) void score_kernel(const float* __restrict__ attW,
                                                    char* __restrict__ ws) {
  const int bid = blockIdx.x;
  const int b = bid >> 1, sh = bid & 1;
  const int tid = threadIdx.x, wv = tid >> 6, lane = tid & 63;
  __shared__ float aW[601];
  for (int i = tid; i < 601; i += 256) aW[i] = attW[i];
  const float* memv = (const float*)(ws + oMemV) + (size_t)b * S_ * 600;
  const float ml = (float)((const int*)(ws + oLens))[b];
  const float ll = (float)((const int*)(ws + oLens + 512))[b];
  const float al = (float)((const int*)(ws + oLens + 1024))[b];
  __syncthreads();
  float* scg = (float*)(ws + oSc) + b * S_;
  for (int s = sh * 128 + wv; s < sh * 128 + 128; s += 4) {
    const float* rowp = memv + (size_t)s * 600;
    float acc = 0.f;
    for (int d = lane; d < 600; d += 64) acc += rowp[d] * aW[d];
    for (int off = 32; off; off >>= 1) acc += __shfl_xor(acc, off);
    if (lane == 0) {
      float p = (float)s;
      bool inl = p < ll;
      bool inr = (p >= ll + al) && (p < ml);
      float u = inl ? (p - ll) : (inr ? (p - ll - al + 1.f) : 0.f);
      scg[s] = acc + u * aW[600];
    }
  }
}

// ---------------- K6: softmax + weighted sum -> i^T ----------------
__global__ __launch_bounds__(256) void attn_kernel(char* __restrict__ ws) {
  const int bid = blockIdx.x;
  const int b = bid >> 1, dh = bid & 1;
  const int tid = threadIdx.x, wv = tid >> 6, lane = tid & 63;
  __shared__ float alpha[256];
  __shared__ float red[8];
  const float* scg = (const float*)(ws + oSc) + b * S_;
  float v = scg[tid];
  float mx = v;
  for (int off = 32; off; off >>= 1) mx = fmaxf(mx, __shfl_xor(mx, off));
  if (lane == 0) red[wv] = mx;
  __syncthreads();
  mx = fmaxf(fmaxf(red[0], red[1]), fmaxf(red[2], red[3]));
  float e = __expf(v - mx);
  float sm = e;
  for (int off = 32; off; off >>= 1) sm += __shfl_xor(sm, off);
  if (lane == 0) red[4 + wv] = sm;
  __syncthreads();
  float tot = red[4] + red[5] + red[6] + red[7];
  alpha[tid] = e / tot;
  const float ml = (float)((const int*)(ws + oLens))[b];
  const float ll = (float)((const int*)(ws + oLens + 512))[b];
  const float al = (float)((const int*)(ws + oLens + 1024))[b];
  __syncthreads();
  const float* memv = (const float*)(ws + oMemV) + (size_t)b * S_ * 600;
  float* iT = (float*)(ws + oIT);
  const int d0 = dh * 301, d1 = dh ? 601 : 301;
  for (int d = d0 + tid; d < d1; d += 256) {
    float acc = 0.f;
    if (d < 600) {
      for (int s = 0; s < 256; ++s) acc += alpha[s] * memv[(size_t)s * 600 + d];
    } else {
      for (int s = 0; s < 256; ++s) {
        float p = (float)s;
        bool inl = p < ll;
        bool inr = (p >= ll + al) && (p < ml);
        float u = inl ? (p - ll) : (inr ? (p - ll - al + 1.f) : 0.f);
        acc += alpha[s] * u;
      }
    }
    iT[d * 128 + b] = acc;
  }
}

// ---------------- K7: GRU gi (once) ----------------
__global__ __launch_bounds__(256) void gi_kernel(const float* __restrict__ Wih,
                                                 const float* __restrict__ bih,
                                                 char* __restrict__ ws) {
  int idx = blockIdx.x * 256 + threadIdx.x;
  int r = idx >> 7, b = idx & 127;
  if (r >= 900) return;
  const float* iT = (const float*)(ws + oIT);
  const float* wr = Wih + (size_t)r * 601;
  float acc = bih[r];
  for (int d = 0; d < 601; ++d) acc += iT[d * 128 + b] * wr[d];
  ((float*)(ws + oGi))[r * 128 + b] = acc;
}

// ---------------- K8: GRU gh (per hop) ----------------
__global__ __launch_bounds__(256) void gh_kernel(const float* __restrict__ Whh,
                                                 const float* __restrict__ bhh,
                                                 char* __restrict__ ws) {
  int idx = blockIdx.x * 256 + threadIdx.x;
  int r = idx >> 7, b = idx & 127;
  if (r >= 900) return;
  const float* et = (const float*)(ws + oEt);
  const float* wr = Whh + (size_t)r * 300;
  float acc = bhh[r];
  for (int u = 0; u < 300; ++u) acc += et[u * 128 + b] * wr[u];
  ((float*)(ws + oGh))[r * 128 + b] = acc;
}

// ---------------- K9: GRU update (per hop) ----------------
__global__ __launch_bounds__(256) void up_kernel(char* __restrict__ ws) {
  int idx = blockIdx.x * 256 + threadIdx.x;
  int u = idx >> 7, b = idx & 127;
  if (u >= 300) return;
  const float* gi = (const float*)(ws + oGi);
  const float* gh = (const float*)(ws + oGh);
  float* et = (float*)(ws + oEt);
  float rr = sigm(gi[u * 128 + b] + gh[u * 128 + b]);
  float zz = sigm(gi[(300 + u) * 128 + b] + gh[(300 + u) * 128 + b]);
  float nn = tanh_f(gi[(600 + u) * 128 + b] + rr * gh[(600 + u) * 128 + b]);
  float old = et[u * 128 + b];
  et[u * 128 + b] = (1.f - zz) * nn + zz * old;
}

// ---------------- K10: dense head ----------------
__global__ __launch_bounds__(384) void dense_kernel(const float* __restrict__ dW,
                                                    const float* __restrict__ dB,
                                                    float* __restrict__ out,
                                                    const char* __restrict__ ws) {
  int tid = threadIdx.x;
  if (tid >= 384) return;
  int b = tid / 3, c = tid - 3 * (tid / 3);
  const float* et = (const float*)(ws + oEt);
  float acc = dB[c];
  const float* wr = dW + c * 300;
  for (int u = 0; u < 300; ++u) acc += et[u * 128 + b] * wr[u];
  out[b * 3 + c] = acc;
}

extern "C" void kernel_launch(void* const* d_in, const int* in_sizes, int n_in,
                              void* d_out, int out_size, void* d_ws, size_t ws_size,
                              hipStream_t stream) {
  const int* text = (const int*)d_in[0];
  const int* aspect = (const int*)d_in[1];
  const int* leftc = (const int*)d_in[2];
  const float* emb = (const float*)d_in[3];
  const float* WihF = (const float*)d_in[4];
  const float* WhhF = (const float*)d_in[5];
  const float* bihF = (const float*)d_in[6];
  const float* bhhF = (const float*)d_in[7];
  const float* WihB = (const float*)d_in[8];
  const float* WhhB = (const float*)d_in[9];
  const float* bihB = (const float*)d_in[10];
  const float* bhhB = (const float*)d_in[11];
  const float* attW = (const float*)d_in[12];
  const float* gruWih = (const float*)d_in[14];
  const float* gruWhh = (const float*)d_in[15];
  const float* gruBih = (const float*)d_in[16];
  const float* gruBhh = (const float*)d_in[17];
  const float* denseW = (const float*)d_in[18];
  const float* denseB = (const float*)d_in[19];
  float* out = (float*)d_out;
  char* ws = (char*)d_ws;
  if (ws_size < WS_NEED) return;

  init_kernel<<<67, 256, 0, stream>>>(text, aspect, leftc, ws);
  pack_kernel<<<6420, 256, 0, stream>>>(WihF, WhhF, bihF, bhhF, WihB, WhhB, bihB, bhhB, ws);
  gather_kernel<<<2 * B_ * S_, KPAD, 0, stream>>>(text, emb, ws);
  lstm_kernel<<<NBLK, 256, 0, stream>>>(ws);
  score_kernel<<<2 * B_, 256, 0, stream>>>(attW, ws);
  attn_kernel<<<2 * B_, 256, 0, stream>>>(ws);
  gi_kernel<<<450, 256, 0, stream>>>(gruWih, gruBih, ws);
  for (int h = 0; h < 3; ++h) {
    gh_kernel<<<450, 256, 0, stream>>>(gruWhh, gruBhh, ws);
    up_kernel<<<150, 256, 0, stream>>>(ws);
  }
  dense_kernel<<<1, 384, 0, stream>>>(denseW, denseB, out, ws);
}

// Round 7
// 1958.200 us; speedup vs baseline: 1.4176x; 1.1848x over previous
//
#include <hip/hip_runtime.h>
#include <hip/hip_bf16.h>
#include <math.h>

#define B_ 128
#define S_ 256
#define A_ 8
#define E_ 300
#define H_ 300
#define KPAD 320
#define NGU 16     // unit groups per direction
#define NGB 4      // batch groups (32 rows each)
#define NCOL 80    // padded gate-cols per unit group (<=80 real)
#define WROW 648   // LDS row stride (u16) for W slice rows
#define HROW 328   // LDS row stride (u16) for h panel (320 + 8 pad)
#define NBLK 128   // 2 dir * 4 gb * 16 gu

typedef unsigned short u16;
typedef unsigned int u32;
typedef unsigned long long u64;
typedef __attribute__((ext_vector_type(8))) short short8;
typedef __attribute__((ext_vector_type(4))) float floatx4;
typedef __attribute__((ext_vector_type(4))) unsigned int u32x4;

#define MFMA16(a, b, c) __builtin_amdgcn_mfma_f32_16x16x32_bf16((a), (b), (c), 0, 0, 0)

__device__ __host__ __forceinline__ int gu_cnt(int g) { return g < 6 ? 20 : 18; }
__device__ __host__ __forceinline__ int gu_u0(int g) { return g < 6 ? 20 * g : 120 + 18 * (g - 6); }

// ---- workspace layout (bytes) ----
static constexpr size_t oLens = 0;                       // mem_len[128], left_len[128], asp_len[128]
static constexpr size_t oFlg  = 1536;                    // flags [dir2][gb4][gu16] @16B spacing
static constexpr size_t oH    = 4096;                    // h bf16 [parity2][dir2][128][320] = 327680
static constexpr size_t oMemX = 331776;                  // x bf16 [dir2][128][256][320] = 41943040
static constexpr size_t oWp   = 42274816;                // packed W bf16 [2][16][80][640] = 3276800
static constexpr size_t oBp   = 45551616;                // packed bias f32 [2][16][80] = 10240
static constexpr size_t oMemV = 45561856;                // locationed memory v f32 [128][256][600] = 78643200
static constexpr size_t oIT   = 124205056;               // i^T f32 [601][128]
static constexpr size_t oGi   = 124512768;               // gi^T f32 [900][128]
static constexpr size_t oGh   = 124973568;               // gh^T f32 [900][128]
static constexpr size_t oEt   = 125434368;               // et^T f32 [300][128]
static constexpr size_t oSc   = 125587968;               // scores f32 [128][256]
static constexpr size_t WS_NEED = 125719040;             // ~120 MB

__device__ __forceinline__ u16 f2bf(float f) {
  union { float f; unsigned u; } v; v.f = f;
  unsigned r = (v.u + 0x7FFFu + ((v.u >> 16) & 1u)) >> 16;
  return (u16)r;
}
__device__ __forceinline__ float sigm(float x) { return 1.f / (1.f + __expf(-x)); }
__device__ __forceinline__ float tanh_f(float x) {
  x = fminf(15.f, fmaxf(-15.f, x));
  float e = __expf(2.f * x);
  return (e - 1.f) / (e + 1.f);
}

// ---------------- K1: lengths + zero init ----------------
__global__ __launch_bounds__(256) void init_kernel(const int* __restrict__ text,
                                                   const int* __restrict__ aspect,
                                                   const int* __restrict__ leftc,
                                                   char* __restrict__ ws) {
  const int bid = blockIdx.x, tid = threadIdx.x;
  if (bid == 0) {
    if (tid < B_) {
      int c = 0; const int* p = text + tid * S_;
      for (int s = 0; s < S_; ++s) c += (p[s] != 0);
      ((int*)(ws + oLens))[tid] = c;
    }
  } else if (bid == 1) {
    if (tid < B_) {
      int c = 0; const int* p = leftc + tid * S_;
      for (int s = 0; s < S_; ++s) c += (p[s] != 0);
      ((int*)(ws + oLens + 512))[tid] = c;
    }
  } else if (bid == 2) {
    if (tid < B_) {
      int c = 0; const int* p = aspect + tid * A_;
      for (int s = 0; s < A_; ++s) c += (p[s] != 0);
      ((int*)(ws + oLens + 1024))[tid] = c;
    }
  } else {
    const int CW = 640, HW = 327680 / 4, EW = 153600 / 4;   // [1536,4096) flags
    const int total = CW + HW + EW;
    for (int i = (bid - 3) * 256 + tid; i < total; i += 64 * 256) {
      if (i < CW)            ((unsigned*)(ws + oFlg))[i] = 0u;
      else if (i < CW + HW)  ((unsigned*)(ws + oH))[i - CW] = 0u;
      else                   ((unsigned*)(ws + oEt))[i - CW - HW] = 0u;
    }
  }
}

// ---------------- K2: weight/bias pre-pack to bf16 ----------------
__global__ __launch_bounds__(256) void pack_kernel(
    const float* __restrict__ WihF, const float* __restrict__ WhhF,
    const float* __restrict__ bihF, const float* __restrict__ bhhF,
    const float* __restrict__ WihB, const float* __restrict__ WhhB,
    const float* __restrict__ bihB, const float* __restrict__ bhhB,
    char* __restrict__ ws) {
  const int WTOT = 2 * NGU * NCOL * 640;
  int idx = blockIdx.x * 256 + threadIdx.x;
  if (idx < WTOT) {
    int k = idx % 640;
    int n = (idx / 640) % NCOL;
    int g = (idx / (640 * NCOL)) % NGU;
    int dir = idx / (640 * NCOL * NGU);
    float v = 0.f;
    const int cnt = gu_cnt(g), u0 = gu_u0(g);
    if (n < cnt * 4) {
      int col = (n & 3) * 300 + u0 + (n >> 2);
      const float* Wih = dir ? WihB : WihF;
      const float* Whh = dir ? WhhB : WhhF;
      if (k < 300)                  v = Wih[(size_t)col * 300 + k];
      else if (k >= 320 && k < 620) v = Whh[(size_t)col * 300 + (k - 320)];
    }
    ((u16*)(ws + oWp))[idx] = f2bf(v);
  } else {
    int j = idx - WTOT;
    if (j < 2 * NGU * NCOL) {
      int n = j % NCOL; int g = (j / NCOL) % NGU; int dir = j / (NCOL * NGU);
      float v = 0.f;
      const int cnt = gu_cnt(g), u0 = gu_u0(g);
      if (n < cnt * 4) {
        int col = (n & 3) * 300 + u0 + (n >> 2);
        v = (dir ? bihB : bihF)[col] + (dir ? bhhB : bhhF)[col];
      }
      ((float*)(ws + oBp))[j] = v;
    }
  }
}

// ---------------- K3: embedding gather (bwd dir pre-reversed) ----------------
__global__ __launch_bounds__(KPAD) void gather_kernel(const int* __restrict__ text,
                                                      const float* __restrict__ emb,
                                                      char* __restrict__ ws) {
  const int bid = blockIdx.x;
  const int t = bid & 255;
  const int b = (bid >> 8) & 127;
  const int dir = bid >> 15;
  const int len = ((const int*)(ws + oLens))[b];
  const int tp = (dir == 0) ? t : ((t < len) ? (len - 1 - t) : t);
  const int tok = text[b * S_ + tp];
  u16* dst = (u16*)(ws + oMemX) + ((size_t)((dir * B_ + b) * S_ + t)) * KPAD;
  const float* src = emb + (size_t)tok * E_;
  const int k = threadIdx.x;
  float v = (k < E_) ? src[k] : 0.f;
  dst[k] = f2bf(v);
}

// ---------------- K4: persistent BiLSTM ----------------
// Grid 128 = [dir2][gb4][gu16]; pods of 16 blocks share (dir,gb).
// h exchange at agent scope (sc1), but DEDUPLICATED + WIDE: each block stages
// its pod's unique 20KB h-panel into LDS with global_load_dwordx4 sc1
// (1280 transactions/block/step vs 5120 in R5), MFMA A-frags read from LDS.
// Poll loop backs off with s_sleep to unload the coherence fabric.
__global__ __launch_bounds__(256, 1) void lstm_kernel(char* __restrict__ ws) {
  const int bid = (int)blockIdx.x;
  const int dir = bid >> 6;
  const int gb  = (bid >> 4) & 3;
  const int g   = bid & 15;
  const int cnt = gu_cnt(g), u0 = gu_u0(g);
  const int npair = cnt >> 1;           // 10 or 9
  const int tid = threadIdx.x;
  const int wv = tid >> 6;              // 0..3
  const int lane = tid & 63;
  const int quad = lane >> 4;
  const int l16 = lane & 15;
  const int Mtile = wv >> 1;            // rows [Mtile*16, +16)
  const int nt0 = (wv & 1) ? 3 : 0;     // N-tile set {0,1,2} or {3,4}
  const int ntc = (wv & 1) ? 2 : 3;

  const u64* __restrict__ Wp64 = (const u64*)(ws + oWp) + (size_t)(dir * NGU + g) * NCOL * 160;
  const float* __restrict__ Bpk = (const float*)(ws + oBp) + (dir * NGU + g) * NCOL;
  const u16* __restrict__ memx = (const u16*)(ws + oMemX) + (size_t)dir * B_ * S_ * KPAD;
  const u16* __restrict__ hb16 = (const u16*)(ws + oH);
  u32* __restrict__ hb32 = (u32*)(ws + oH);
  float* __restrict__ memv = (float*)(ws + oMemV);
  u32* __restrict__ flags = (u32*)(ws + oFlg) + (size_t)(dir * 4 + gb) * 64;  // 16 slots @16B

  __shared__ __align__(16) u16 Wlds[NCOL * WROW];          // 103680 B
  __shared__ __align__(16) u16 hLds[32 * HROW];            // 20992 B
  __shared__ float gatesLds[32 * 81];                      // 10368 B
  __shared__ float cS[640];
  __shared__ float hS[640];
  __shared__ float biasS[NCOL];
  __shared__ int lenS[32], llS[32], alS[32];

  for (int i = tid; i < NCOL * 160; i += 256) {
    int n = i / 160, k4 = i - n * 160;
    ((u64*)Wlds)[n * 162 + k4] = Wp64[i];
  }
  for (int i = tid; i < 640; i += 256) { cS[i] = 0.f; hS[i] = 0.f; }
  if (tid < NCOL) biasS[tid] = Bpk[tid];
  if (tid < 32) {
    lenS[tid] = ((const int*)(ws + oLens))[gb * 32 + tid];
    llS[tid]  = ((const int*)(ws + oLens + 512))[gb * 32 + tid];
    alS[tid]  = ((const int*)(ws + oLens + 1024))[gb * 32 + tid];
  }
  __syncthreads();

  const int row = gb * 32 + Mtile * 16 + l16;   // global batch row for A-frags
  const u16* wq = Wlds + l16 * WROW + quad * 8; // per-lane column n = ntile*16+l16

  // per-thread staging geometry (constant over t): 1280 x 16B chunks, 5/thread
  int eoff[5]; u16* ldst[5];
  #pragma unroll
  for (int it = 0; it < 5; ++it) {
    int e = (it * 256 + tid) * 8;            // element offset in the 32x320 panel
    int r = e / KPAD, c = e - r * KPAD;
    eoff[it] = e;
    ldst[it] = hLds + r * HROW + c;
  }
  const u16* hA = hLds + (Mtile * 16 + l16) * HROW + quad * 8;  // A-frag base

  // prefetch x fragments for t = 0
  short8 xv[10];
  {
    const u16* xr = memx + ((size_t)row * S_) * KPAD + quad * 8;
    #pragma unroll
    for (int kk = 0; kk < 10; ++kk) xv[kk] = *(const short8*)(xr + kk * 32);
  }

  for (int t = 0; t < S_; ++t) {
    if (t > 0) {
      if (wv == 0) {
        const u32 target = (u32)t;
        u32 f;
        bool first = true;
        do {
          if (!first) __builtin_amdgcn_s_sleep(1);   // back off the fabric
          first = false;
          f = 0xFFFFFFFFu;
          if (lane < NGU)
            f = __hip_atomic_load(&flags[lane * 4], __ATOMIC_RELAXED, __HIP_MEMORY_SCOPE_AGENT);
        } while (!__all((int)(f >= target)));
      }
      __syncthreads();
      __builtin_amdgcn_fence(__ATOMIC_ACQUIRE, "workgroup");
    }

    // issue the 5 wide coherent loads of the pod's h panel (16B sc1 each)
    u32x4 hstash[5];
    {
      const u16* hpan = hb16 + (((size_t)(t & 1) * 2 + dir) * B_ + gb * 32) * KPAD;
      #pragma unroll
      for (int it = 0; it < 5; ++it) {
        asm volatile("global_load_dwordx4 %0, %1, off sc1"
                     : "=v"(hstash[it]) : "v"(hpan + eoff[it]) : "memory");
      }
    }

    floatx4 acc[3];
    acc[0] = (floatx4){0.f, 0.f, 0.f, 0.f}; acc[1] = acc[0]; acc[2] = acc[0];
    // x-part (prefetched regs) — overlaps the h-load round trip
    #pragma unroll
    for (int kk = 0; kk < 10; ++kk) {
      const int ko = kk * 32;
      #pragma unroll
      for (int j = 0; j < 3; ++j) {
        if (j < ntc)
          acc[j] = MFMA16(xv[kk], *(const short8*)(wq + (nt0 + j) * 16 * WROW + ko), acc[j]);
      }
    }

    // land h into LDS
    asm volatile("s_waitcnt vmcnt(0)" ::: "memory");
    #pragma unroll
    for (int it = 0; it < 5; ++it) *(u32x4*)ldst[it] = hstash[it];
    __syncthreads();

    // h-part: A-frags from LDS
    #pragma unroll
    for (int kk = 0; kk < 10; ++kk) {
      const short8 av = *(const short8*)(hA + kk * 32);
      const int ko = 320 + kk * 32;
      #pragma unroll
      for (int j = 0; j < 3; ++j) {
        if (j < ntc)
          acc[j] = MFMA16(av, *(const short8*)(wq + (nt0 + j) * 16 * WROW + ko), acc[j]);
      }
    }

    // stage gates to LDS (C layout: col=lane&15, row=quad*4+reg)
    #pragma unroll
    for (int j = 0; j < 3; ++j) {
      if (j < ntc) {
        const int colb = (nt0 + j) * 16 + l16;
        const int rb = Mtile * 16 + quad * 4;
        #pragma unroll
        for (int r = 0; r < 4; ++r)
          gatesLds[(rb + r) * 81 + colb] = acc[j][r];
      }
    }
    __syncthreads();

    // elementwise LSTM cell: 32 rows * npair unit-pairs (<=320 items)
    const int nxt = (t + 1) & 1;
    float2 sv[2]; float* sa[2]; bool sval[2];
    #pragma unroll
    for (int z = 0; z < 2; ++z) {
      const int it = tid + z * 256;
      sval[z] = (it < 32 * npair);
      if (!sval[z]) continue;
      const int bl = it & 31;
      const int pl = it >> 5;
      const int ul0 = pl * 2;
      const int len = lenS[bl];
      const bool m = (t < len);
      const float* gp = gatesLds + bl * 81 + ul0 * 4;
      const float* bp = biasS + ul0 * 4;
      float h0K, h1K, h0N, h1N;
      {
        float ig = sigm(gp[0] + bp[0]);
        float fg = sigm(gp[1] + bp[1]);
        float gt = tanh_f(gp[2] + bp[2]);
        float og = sigm(gp[3] + bp[3]);
        float cOld = cS[ul0 * 32 + bl], hOld = hS[ul0 * 32 + bl];
        float cNew = fg * cOld + ig * gt;
        float hNew = og * tanh_f(cNew);
        cS[ul0 * 32 + bl] = m ? cNew : cOld;
        h0K = m ? hNew : hOld;
        hS[ul0 * 32 + bl] = h0K;
        h0N = m ? hNew : 0.f;
      }
      {
        float ig = sigm(gp[4] + bp[4]);
        float fg = sigm(gp[5] + bp[5]);
        float gt = tanh_f(gp[6] + bp[6]);
        float og = sigm(gp[7] + bp[7]);
        float cOld = cS[(ul0 + 1) * 32 + bl], hOld = hS[(ul0 + 1) * 32 + bl];
        float cNew = fg * cOld + ig * gt;
        float hNew = og * tanh_f(cNew);
        cS[(ul0 + 1) * 32 + bl] = m ? cNew : cOld;
        h1K = m ? hNew : hOld;
        hS[(ul0 + 1) * 32 + bl] = h1K;
        h1N = m ? hNew : 0.f;
      }
      const int bglob = gb * 32 + bl;
      u32 packed = (u32)f2bf(h0K) | ((u32)f2bf(h1K) << 16);
      __hip_atomic_store(&hb32[(((size_t)nxt * 2 + dir) * B_ + bglob) * 160 + ((u0 + ul0) >> 1)],
                         packed, __ATOMIC_RELAXED, __HIP_MEMORY_SCOPE_AGENT);
      int pos = (dir == 0) ? t : (m ? (len - 1 - t) : t);
      float ml = (float)len, ll = (float)llS[bl], al = (float)alS[bl];
      float p = (float)pos;
      float wl;
      if (p < ll) wl = 1.f - (ll - p) / ml;
      else if ((p >= ll + al) && (p < ml)) wl = 1.f - (p - ll - al + 1.f) / ml;
      else wl = 1.f;
      sv[z] = make_float2(h0N * wl, h1N * wl);
      sa[z] = &memv[((size_t)bglob * S_ + pos) * 600 + dir * 300 + u0 + ul0];
    }

    __builtin_amdgcn_fence(__ATOMIC_RELEASE, "workgroup");
    __syncthreads();  // vmcnt(0) drain: h stores are at the coherence point
    if (tid == 0)
      __hip_atomic_store(&flags[g * 4], (u32)(t + 1), __ATOMIC_RELAXED, __HIP_MEMORY_SCOPE_AGENT);

    // deferred memv stores + next-step x prefetch — overlap the poll window
    #pragma unroll
    for (int z = 0; z < 2; ++z)
      if (sval[z]) *(float2*)sa[z] = sv[z];
    if (t + 1 < S_) {
      const u16* xr = memx + ((size_t)row * S_ + (t + 1)) * KPAD + quad * 8;
      #pragma unroll
      for (int kk = 0; kk < 10; ++kk) xv[kk] = *(const short8*)(xr + kk * 32);
    }
  }
}

// ---------------- K5: attention scores ----------------
__global__ __launch_bounds__(256) void score_kernel(const float* __restrict__ attW,
                                                    char* __restrict__ ws) {
  const int bid = blockIdx.x;
  const int b = bid >> 1, sh = bid & 1;
  const int tid = threadIdx.x, wv = tid >> 6, lane = tid & 63;
  __shared__ float aW[601];
  for (int i = tid; i < 601; i += 256) aW[i] = attW[i];
  const float* memv = (const float*)(ws + oMemV) + (size_t)b * S_ * 600;
  const float ml = (float)((const int*)(ws + oLens))[b];
  const float ll = (float)((const int*)(ws + oLens + 512))[b];
  const float al = (float)((const int*)(ws + oLens + 1024))[b];
  __syncthreads();
  float* scg = (float*)(ws + oSc) + b * S_;
  for (int s = sh * 128 + wv; s < sh * 128 + 128; s += 4) {
    const float* rowp = memv + (size_t)s * 600;
    float acc = 0.f;
    for (int d = lane; d < 600; d += 64) acc += rowp[d] * aW[d];
    for (int off = 32; off; off >>= 1) acc += __shfl_xor(acc, off);
    if (lane == 0) {
      float p = (float)s;
      bool inl = p < ll;
      bool inr = (p >= ll + al) && (p < ml);
      float u = inl ? (p - ll) : (inr ? (p - ll - al + 1.f) : 0.f);
      scg[s] = acc + u * aW[600];
    }
  }
}

// ---------------- K6: softmax + weighted sum -> i^T ----------------
__global__ __launch_bounds__(256) void attn_kernel(char* __restrict__ ws) {
  const int bid = blockIdx.x;
  const int b = bid >> 1, dh = bid & 1;
  const int tid = threadIdx.x, wv = tid >> 6, lane = tid & 63;
  __shared__ float alpha[256];
  __shared__ float red[8];
  const float* scg = (const float*)(ws + oSc) + b * S_;
  float v = scg[tid];
  float mx = v;
  for (int off = 32; off; off >>= 1) mx = fmaxf(mx, __shfl_xor(mx, off));
  if (lane == 0) red[wv] = mx;
  __syncthreads();
  mx = fmaxf(fmaxf(red[0], red[1]), fmaxf(red[2], red[3]));
  float e = __expf(v - mx);
  float sm = e;
  for (int off = 32; off; off >>= 1) sm += __shfl_xor(sm, off);
  if (lane == 0) red[4 + wv] = sm;
  __syncthreads();
  float tot = red[4] + red[5] + red[6] + red[7];
  alpha[tid] = e / tot;
  const float ml = (float)((const int*)(ws + oLens))[b];
  const float ll = (float)((const int*)(ws + oLens + 512))[b];
  const float al = (float)((const int*)(ws + oLens + 1024))[b];
  __syncthreads();
  const float* memv = (const float*)(ws + oMemV) + (size_t)b * S_ * 600;
  float* iT = (float*)(ws + oIT);
  const int d0 = dh * 301, d1 = dh ? 601 : 301;
  for (int d = d0 + tid; d < d1; d += 256) {
    float acc = 0.f;
    if (d < 600) {
      for (int s = 0; s < 256; ++s) acc += alpha[s] * memv[(size_t)s * 600 + d];
    } else {
      for (int s = 0; s < 256; ++s) {
        float p = (float)s;
        bool inl = p < ll;
        bool inr = (p >= ll + al) && (p < ml);
        float u = inl ? (p - ll) : (inr ? (p - ll - al + 1.f) : 0.f);
        acc += alpha[s] * u;
      }
    }
    iT[d * 128 + b] = acc;
  }
}

// ---------------- K7: GRU gi (once) ----------------
__global__ __launch_bounds__(256) void gi_kernel(const float* __restrict__ Wih,
                                                 const float* __restrict__ bih,
                                                 char* __restrict__ ws) {
  int idx = blockIdx.x * 256 + threadIdx.x;
  int r = idx >> 7, b = idx & 127;
  if (r >= 900) return;
  const float* iT = (const float*)(ws + oIT);
  const float* wr = Wih + (size_t)r * 601;
  float acc = bih[r];
  for (int d = 0; d < 601; ++d) acc += iT[d * 128 + b] * wr[d];
  ((float*)(ws + oGi))[r * 128 + b] = acc;
}

// ---------------- K8: GRU gh (per hop) ----------------
__global__ __launch_bounds__(256) void gh_kernel(const float* __restrict__ Whh,
                                                 const float* __restrict__ bhh,
                                                 char* __restrict__ ws) {
  int idx = blockIdx.x * 256 + threadIdx.x;
  int r = idx >> 7, b = idx & 127;
  if (r >= 900) return;
  const float* et = (const float*)(ws + oEt);
  const float* wr = Whh + (size_t)r * 300;
  float acc = bhh[r];
  for (int u = 0; u < 300; ++u) acc += et[u * 128 + b] * wr[u];
  ((float*)(ws + oGh))[r * 128 + b] = acc;
}

// ---------------- K9: GRU update (per hop) ----------------
__global__ __launch_bounds__(256) void up_kernel(char* __restrict__ ws) {
  int idx = blockIdx.x * 256 + threadIdx.x;
  int u = idx >> 7, b = idx & 127;
  if (u >= 300) return;
  const float* gi = (const float*)(ws + oGi);
  const float* gh = (const float*)(ws + oGh);
  float* et = (float*)(ws + oEt);
  float rr = sigm(gi[u * 128 + b] + gh[u * 128 + b]);
  float zz = sigm(gi[(300 + u) * 128 + b] + gh[(300 + u) * 128 + b]);
  float nn = tanh_f(gi[(600 + u) * 128 + b] + rr * gh[(600 + u) * 128 + b]);
  float old = et[u * 128 + b];
  et[u * 128 + b] = (1.f - zz) * nn + zz * old;
}

// ---------------- K10: dense head ----------------
__global__ __launch_bounds__(384) void dense_kernel(const float* __restrict__ dW,
                                                    const float* __restrict__ dB,
                                                    float* __restrict__ out,
                                                    const char* __restrict__ ws) {
  int tid = threadIdx.x;
  if (tid >= 384) return;
  int b = tid / 3, c = tid - 3 * (tid / 3);
  const float* et = (const float*)(ws + oEt);
  float acc = dB[c];
  const float* wr = dW + c * 300;
  for (int u = 0; u < 300; ++u) acc += et[u * 128 + b] * wr[u];
  out[b * 3 + c] = acc;
}

extern "C" void kernel_launch(void* const* d_in, const int* in_sizes, int n_in,
                              void* d_out, int out_size, void* d_ws, size_t ws_size,
                              hipStream_t stream) {
  const int* text = (const int*)d_in[0];
  const int* aspect = (const int*)d_in[1];
  const int* leftc = (const int*)d_in[2];
  const float* emb = (const float*)d_in[3];
  const float* WihF = (const float*)d_in[4];
  const float* WhhF = (const float*)d_in[5];
  const float* bihF = (const float*)d_in[6];
  const float* bhhF = (const float*)d_in[7];
  const float* WihB = (const float*)d_in[8];
  const float* WhhB = (const float*)d_in[9];
  const float* bihB = (const float*)d_in[10];
  const float* bhhB = (const float*)d_in[11];
  const float* attW = (const float*)d_in[12];
  const float* gruWih = (const float*)d_in[14];
  const float* gruWhh = (const float*)d_in[15];
  const float* gruBih = (const float*)d_in[16];
  const float* gruBhh = (const float*)d_in[17];
  const float* denseW = (const float*)d_in[18];
  const float* denseB = (const float*)d_in[19];
  float* out = (float*)d_out;
  char* ws = (char*)d_ws;
  if (ws_size < WS_NEED) return;

  init_kernel<<<67, 256, 0, stream>>>(text, aspect, leftc, ws);
  pack_kernel<<<6420, 256, 0, stream>>>(WihF, WhhF, bihF, bhhF, WihB, WhhB, bihB, bhhB, ws);
  gather_kernel<<<2 * B_ * S_, KPAD, 0, stream>>>(text, emb, ws);
  lstm_kernel<<<NBLK, 256, 0, stream>>>(ws);
  score_kernel<<<2 * B_, 256, 0, stream>>>(attW, ws);
  attn_kernel<<<2 * B_, 256, 0, stream>>>(ws);
  gi_kernel<<<450, 256, 0, stream>>>(gruWih, gruBih, ws);
  for (int h = 0; h < 3; ++h) {
    gh_kernel<<<450, 256, 0, stream>>>(gruWhh, gruBhh, ws);
    up_kernel<<<150, 256, 0, stream>>>(ws);
  }
  dense_kernel<<<1, 384, 0, stream>>>(denseW, denseB, out, ws);
}

// Round 8
// 1910.587 us; speedup vs baseline: 1.4530x; 1.0249x over previous
//
#include <hip/hip_runtime.h>
#include <hip/hip_bf16.h>
#include <math.h>

#define B_ 128
#define S_ 256
#define A_ 8
#define E_ 300
#define H_ 300
#define KPAD 320
#define NGU 16     // unit groups per direction
#define NCOL 80    // padded gate-cols per unit group (<=80 real)
#define WROW 648   // LDS row stride (u16) for W slice rows
#define HROW 328   // LDS row stride (u16) for h panel (320 + 8 pad)
#define NBLK 128   // 8 pods (dir2 x gb4) x 16 unit-groups

typedef unsigned short u16;
typedef unsigned int u32;
typedef unsigned long long u64;
typedef __attribute__((ext_vector_type(8))) short short8;
typedef __attribute__((ext_vector_type(4))) float floatx4;
typedef __attribute__((ext_vector_type(4))) unsigned int u32x4;

#define MFMA16(a, b, c) __builtin_amdgcn_mfma_f32_16x16x32_bf16((a), (b), (c), 0, 0, 0)

__device__ __host__ __forceinline__ int gu_cnt(int g) { return g < 6 ? 20 : 18; }
__device__ __host__ __forceinline__ int gu_u0(int g) { return g < 6 ? 20 * g : 120 + 18 * (g - 6); }

// ---- workspace layout (bytes) ----
static constexpr size_t oLens = 0;                       // mem_len[128], left_len[128], asp_len[128]
static constexpr size_t oFlg  = 1536;                    // PLAIN flags [pod8][slot16] @16B (2048B)
static constexpr size_t oH    = 4096;                    // h bf16 (sc1 copy) [par2][dir2][128][320] = 327680
static constexpr size_t oMemX = 331776;                  // x bf16 [dir2][128][256][320] = 41943040
static constexpr size_t oWp   = 42274816;                // packed W bf16 [2][16][80][640] = 3276800
static constexpr size_t oBp   = 45551616;                // packed bias f32 [2][16][80] = 10240
static constexpr size_t oMemV = 45561856;                // locationed memory v f32 [128][256][600] = 78643200
static constexpr size_t oIT   = 124205056;               // i^T f32 [601][128]
static constexpr size_t oGi   = 124512768;               // gi^T f32 [900][128]
static constexpr size_t oGh   = 124973568;               // gh^T f32 [900][128]
static constexpr size_t oEt   = 125434368;               // et^T f32 [300][128]
static constexpr size_t oSc   = 125587968;               // scores f32 [128][256]
static constexpr size_t oMirr = 125719040;               // MIRROR flags (sc1) [pod8][slot16] @16B (2048B)
static constexpr size_t oHL2  = 125721088;               // h bf16 (plain/L2 copy) = 327680
static constexpr size_t WS_NEED = 126048768;             // ~120 MB

__device__ __forceinline__ u16 f2bf(float f) {
  union { float f; unsigned u; } v; v.f = f;
  unsigned r = (v.u + 0x7FFFu + ((v.u >> 16) & 1u)) >> 16;
  return (u16)r;
}
__device__ __forceinline__ float sigm(float x) { return 1.f / (1.f + __expf(-x)); }
__device__ __forceinline__ float tanh_f(float x) {
  x = fminf(15.f, fmaxf(-15.f, x));
  float e = __expf(2.f * x);
  return (e - 1.f) / (e + 1.f);
}
__device__ __forceinline__ u32 ld_sc0(const u32* p) {   // L1-bypass load (reads own L2)
  u32 v;
  asm volatile("global_load_dword %0, %1, off sc0\n\ts_waitcnt vmcnt(0)"
               : "=v"(v) : "v"(p) : "memory");
  return v;
}

// ---------------- K1: lengths + zero init ----------------
__global__ __launch_bounds__(256) void init_kernel(const int* __restrict__ text,
                                                   const int* __restrict__ aspect,
                                                   const int* __restrict__ leftc,
                                                   char* __restrict__ ws) {
  const int bid = blockIdx.x, tid = threadIdx.x;
  if (bid == 0) {
    if (tid < B_) {
      int c = 0; const int* p = text + tid * S_;
      for (int s = 0; s < S_; ++s) c += (p[s] != 0);
      ((int*)(ws + oLens))[tid] = c;
    }
  } else if (bid == 1) {
    if (tid < B_) {
      int c = 0; const int* p = leftc + tid * S_;
      for (int s = 0; s < S_; ++s) c += (p[s] != 0);
      ((int*)(ws + oLens + 512))[tid] = c;
    }
  } else if (bid == 2) {
    if (tid < B_) {
      int c = 0; const int* p = aspect + tid * A_;
      for (int s = 0; s < A_; ++s) c += (p[s] != 0);
      ((int*)(ws + oLens + 1024))[tid] = c;
    }
  } else {
    const int F1 = 512, F2 = 512, HW = 81920, H2 = 81920, EW = 38400;
    const int total = F1 + F2 + HW + H2 + EW;
    for (int i = (bid - 3) * 256 + tid; i < total; i += 64 * 256) {
      int j = i;
      if (j < F1)            { ((u32*)(ws + oFlg))[j] = 0u; continue; }  j -= F1;
      if (j < F2)            { ((u32*)(ws + oMirr))[j] = 0u; continue; } j -= F2;
      if (j < HW)            { ((u32*)(ws + oH))[j] = 0u; continue; }    j -= HW;
      if (j < H2)            { ((u32*)(ws + oHL2))[j] = 0u; continue; }  j -= H2;
      ((u32*)(ws + oEt))[j] = 0u;
    }
  }
}

// ---------------- K2: weight/bias pre-pack to bf16 ----------------
__global__ __launch_bounds__(256) void pack_kernel(
    const float* __restrict__ WihF, const float* __restrict__ WhhF,
    const float* __restrict__ bihF, const float* __restrict__ bhhF,
    const float* __restrict__ WihB, const float* __restrict__ WhhB,
    const float* __restrict__ bihB, const float* __restrict__ bhhB,
    char* __restrict__ ws) {
  const int WTOT = 2 * NGU * NCOL * 640;
  int idx = blockIdx.x * 256 + threadIdx.x;
  if (idx < WTOT) {
    int k = idx % 640;
    int n = (idx / 640) % NCOL;
    int g = (idx / (640 * NCOL)) % NGU;
    int dir = idx / (640 * NCOL * NGU);
    float v = 0.f;
    const int cnt = gu_cnt(g), u0 = gu_u0(g);
    if (n < cnt * 4) {
      int col = (n & 3) * 300 + u0 + (n >> 2);
      const float* Wih = dir ? WihB : WihF;
      const float* Whh = dir ? WhhB : WhhF;
      if (k < 300)                  v = Wih[(size_t)col * 300 + k];
      else if (k >= 320 && k < 620) v = Whh[(size_t)col * 300 + (k - 320)];
    }
    ((u16*)(ws + oWp))[idx] = f2bf(v);
  } else {
    int j = idx - WTOT;
    if (j < 2 * NGU * NCOL) {
      int n = j % NCOL; int g = (j / NCOL) % NGU; int dir = j / (NCOL * NGU);
      float v = 0.f;
      const int cnt = gu_cnt(g), u0 = gu_u0(g);
      if (n < cnt * 4) {
        int col = (n & 3) * 300 + u0 + (n >> 2);
        v = (dir ? bihB : bihF)[col] + (dir ? bhhB : bhhF)[col];
      }
      ((float*)(ws + oBp))[j] = v;
    }
  }
}

// ---------------- K3: embedding gather (bwd dir pre-reversed) ----------------
__global__ __launch_bounds__(KPAD) void gather_kernel(const int* __restrict__ text,
                                                      const float* __restrict__ emb,
                                                      char* __restrict__ ws) {
  const int bid = blockIdx.x;
  const int t = bid & 255;
  const int b = (bid >> 8) & 127;
  const int dir = bid >> 15;
  const int len = ((const int*)(ws + oLens))[b];
  const int tp = (dir == 0) ? t : ((t < len) ? (len - 1 - t) : t);
  const int tok = text[b * S_ + tp];
  u16* dst = (u16*)(ws + oMemX) + ((size_t)((dir * B_ + b) * S_ + t)) * KPAD;
  const float* src = emb + (size_t)tok * E_;
  const int k = threadIdx.x;
  float v = (k < E_) ? src[k] : 0.f;
  dst[k] = f2bf(v);
}

// ---------------- K4: persistent BiLSTM, optimistic XCD-local exchange ----------------
// pod = blockIdx & 7 (if the CP round-robins workgroups over 8 XCDs, all 16 pod
// members share one XCD/L2). Producers dual-publish h+flag: plain (own L2,
// read by pod-mates via sc0) AND sc1 mirror (coherence point). Consumers poll
// the plain flag; if the sc1 mirror runs ahead of it (pod split across XCDs),
// they permanently fall back to the sc1 path. No placement assumption is
// needed for correctness; the mirror guarantees progress (no deadlock).
__global__ __launch_bounds__(256, 1) void lstm_kernel(char* __restrict__ ws) {
  const int bid = (int)blockIdx.x;
  const int pod = bid & 7;              // {dir, gb}
  const int dir = pod >> 2;
  const int gb  = pod & 3;
  const int g   = bid >> 3;             // unit group 0..15
  const int cnt = gu_cnt(g), u0 = gu_u0(g);
  const int npair = cnt >> 1;           // 10 or 9
  const int tid = threadIdx.x;
  const int wv = tid >> 6;              // 0..3
  const int lane = tid & 63;
  const int quad = lane >> 4;
  const int l16 = lane & 15;
  const int Mtile = wv >> 1;            // rows [Mtile*16, +16)
  const int nt0 = (wv & 1) ? 3 : 0;     // N-tile set {0,1,2} or {3,4}
  const int ntc = (wv & 1) ? 2 : 3;

  const u64* __restrict__ Wp64 = (const u64*)(ws + oWp) + (size_t)(dir * NGU + g) * NCOL * 160;
  const float* __restrict__ Bpk = (const float*)(ws + oBp) + (dir * NGU + g) * NCOL;
  const u16* __restrict__ memx = (const u16*)(ws + oMemX) + (size_t)dir * B_ * S_ * KPAD;
  const u16* __restrict__ hb16 = (const u16*)(ws + oH);
  u32* __restrict__ hb32 = (u32*)(ws + oH);
  const u16* __restrict__ hl16 = (const u16*)(ws + oHL2);
  u32* __restrict__ hl32 = (u32*)(ws + oHL2);
  float* __restrict__ memv = (float*)(ws + oMemV);
  u32* __restrict__ flagsP = (u32*)(ws + oFlg) + (size_t)pod * 64;   // plain, 16 slots @16B
  u32* __restrict__ flagsM = (u32*)(ws + oMirr) + (size_t)pod * 64;  // sc1 mirror

  __shared__ __align__(16) u16 Wlds[NCOL * WROW];          // 103680 B
  __shared__ __align__(16) u16 hLds[32 * HROW];            // 20992 B
  __shared__ float gatesLds[32 * 81];                      // 10368 B
  __shared__ float cS[640];
  __shared__ float hS[640];
  __shared__ float biasS[NCOL];
  __shared__ int lenS[32], llS[32], alS[32];
  __shared__ int remoteS;

  for (int i = tid; i < NCOL * 160; i += 256) {
    int n = i / 160, k4 = i - n * 160;
    ((u64*)Wlds)[n * 162 + k4] = Wp64[i];
  }
  for (int i = tid; i < 640; i += 256) { cS[i] = 0.f; hS[i] = 0.f; }
  if (tid < NCOL) biasS[tid] = Bpk[tid];
  if (tid < 32) {
    lenS[tid] = ((const int*)(ws + oLens))[gb * 32 + tid];
    llS[tid]  = ((const int*)(ws + oLens + 512))[gb * 32 + tid];
    alS[tid]  = ((const int*)(ws + oLens + 1024))[gb * 32 + tid];
  }
  if (tid == 0) remoteS = 0;
  __syncthreads();

  const int row = gb * 32 + Mtile * 16 + l16;   // global batch row for A-frags
  const u16* wq = Wlds + l16 * WROW + quad * 8; // per-lane column n = ntile*16+l16

  // per-thread staging geometry: 1280 x 16B chunks, 5/thread
  int eoff[5]; u16* ldst[5];
  #pragma unroll
  for (int it = 0; it < 5; ++it) {
    int e = (it * 256 + tid) * 8;
    int r = e / KPAD, c = e - r * KPAD;
    eoff[it] = e;
    ldst[it] = hLds + r * HROW + c;
  }
  const u16* hA = hLds + (Mtile * 16 + l16) * HROW + quad * 8;

  // prefetch x fragments for t = 0
  short8 xv[10];
  {
    const u16* xr = memx + ((size_t)row * S_) * KPAD + quad * 8;
    #pragma unroll
    for (int kk = 0; kk < 10; ++kk) xv[kk] = *(const short8*)(xr + kk * 32);
  }

  for (int t = 0; t < S_; ++t) {
    if (t > 0) {
      if (wv == 0) {
        const u32 target = (u32)t;
        int spin = 0;
        while (true) {
          u32 f = 0xFFFFFFFFu;
          const int rm = *(volatile int*)&remoteS;
          if (lane < NGU)
            f = rm ? __hip_atomic_load(&flagsM[lane * 4], __ATOMIC_RELAXED, __HIP_MEMORY_SCOPE_AGENT)
                   : ld_sc0(&flagsP[lane * 4]);
          if (__all((int)(f >= target))) break;
          ++spin;
          if (!rm && spin > 64 && (spin & 15) == 0) {
            // if the sc1 mirror is ahead of the plain copy, our pod spans XCDs
            u32 fm = 0u, fp = 0xFFFFFFFFu;
            if (lane < NGU) {
              fm = __hip_atomic_load(&flagsM[lane * 4], __ATOMIC_RELAXED, __HIP_MEMORY_SCOPE_AGENT);
              fp = ld_sc0(&flagsP[lane * 4]);
            }
            if (__any((int)(fm > fp))) { if (lane == 0) *(volatile int*)&remoteS = 1; }
          }
          if (rm) __builtin_amdgcn_s_sleep(1);
        }
      }
      __syncthreads();
      __builtin_amdgcn_fence(__ATOMIC_ACQUIRE, "workgroup");
    }

    // stage the pod's h panel -> LDS (sc0 from shared L2, or sc1 fallback)
    const int rem = *(volatile int*)&remoteS;
    u32x4 hstash[5];
    {
      const size_t pbase = (((size_t)(t & 1) * 2 + dir) * B_ + gb * 32) * KPAD;
      if (rem) {
        const u16* hpan = hb16 + pbase;
        #pragma unroll
        for (int it = 0; it < 5; ++it)
          asm volatile("global_load_dwordx4 %0, %1, off sc1"
                       : "=v"(hstash[it]) : "v"(hpan + eoff[it]) : "memory");
      } else {
        const u16* hpan = hl16 + pbase;
        #pragma unroll
        for (int it = 0; it < 5; ++it)
          asm volatile("global_load_dwordx4 %0, %1, off sc0"
                       : "=v"(hstash[it]) : "v"(hpan + eoff[it]) : "memory");
      }
    }

    floatx4 acc[3];
    acc[0] = (floatx4){0.f, 0.f, 0.f, 0.f}; acc[1] = acc[0]; acc[2] = acc[0];
    // x-part (prefetched regs) — overlaps the h-load round trip
    #pragma unroll
    for (int kk = 0; kk < 10; ++kk) {
      const int ko = kk * 32;
      #pragma unroll
      for (int j = 0; j < 3; ++j) {
        if (j < ntc)
          acc[j] = MFMA16(xv[kk], *(const short8*)(wq + (nt0 + j) * 16 * WROW + ko), acc[j]);
      }
    }

    // land h into LDS
    asm volatile("s_waitcnt vmcnt(0)" ::: "memory");
    #pragma unroll
    for (int it = 0; it < 5; ++it) *(u32x4*)ldst[it] = hstash[it];
    __syncthreads();

    // h-part: A-frags from LDS
    #pragma unroll
    for (int kk = 0; kk < 10; ++kk) {
      const short8 av = *(const short8*)(hA + kk * 32);
      const int ko = 320 + kk * 32;
      #pragma unroll
      for (int j = 0; j < 3; ++j) {
        if (j < ntc)
          acc[j] = MFMA16(av, *(const short8*)(wq + (nt0 + j) * 16 * WROW + ko), acc[j]);
      }
    }

    // stage gates to LDS (C layout: col=lane&15, row=quad*4+reg)
    #pragma unroll
    for (int j = 0; j < 3; ++j) {
      if (j < ntc) {
        const int colb = (nt0 + j) * 16 + l16;
        const int rb = Mtile * 16 + quad * 4;
        #pragma unroll
        for (int r = 0; r < 4; ++r)
          gatesLds[(rb + r) * 81 + colb] = acc[j][r];
      }
    }
    __syncthreads();

    // elementwise LSTM cell: 32 rows * npair unit-pairs
    const int nxt = (t + 1) & 1;
    float2 sv[2]; float* sa[2]; bool sval[2];
    #pragma unroll
    for (int z = 0; z < 2; ++z) {
      const int it = tid + z * 256;
      sval[z] = (it < 32 * npair);
      if (!sval[z]) continue;
      const int bl = it & 31;
      const int pl = it >> 5;
      const int ul0 = pl * 2;
      const int len = lenS[bl];
      const bool m = (t < len);
      const float* gp = gatesLds + bl * 81 + ul0 * 4;
      const float* bp = biasS + ul0 * 4;
      float h0K, h1K, h0N, h1N;
      {
        float ig = sigm(gp[0] + bp[0]);
        float fg = sigm(gp[1] + bp[1]);
        float gt = tanh_f(gp[2] + bp[2]);
        float og = sigm(gp[3] + bp[3]);
        float cOld = cS[ul0 * 32 + bl], hOld = hS[ul0 * 32 + bl];
        float cNew = fg * cOld + ig * gt;
        float hNew = og * tanh_f(cNew);
        cS[ul0 * 32 + bl] = m ? cNew : cOld;
        h0K = m ? hNew : hOld;
        hS[ul0 * 32 + bl] = h0K;
        h0N = m ? hNew : 0.f;
      }
      {
        float ig = sigm(gp[4] + bp[4]);
        float fg = sigm(gp[5] + bp[5]);
        float gt = tanh_f(gp[6] + bp[6]);
        float og = sigm(gp[7] + bp[7]);
        float cOld = cS[(ul0 + 1) * 32 + bl], hOld = hS[(ul0 + 1) * 32 + bl];
        float cNew = fg * cOld + ig * gt;
        float hNew = og * tanh_f(cNew);
        cS[(ul0 + 1) * 32 + bl] = m ? cNew : cOld;
        h1K = m ? hNew : hOld;
        hS[(ul0 + 1) * 32 + bl] = h1K;
        h1N = m ? hNew : 0.f;
      }
      const int bglob = gb * 32 + bl;
      const size_t hidx = (((size_t)nxt * 2 + dir) * B_ + bglob) * 160 + ((u0 + ul0) >> 1);
      u32 packed = (u32)f2bf(h0K) | ((u32)f2bf(h1K) << 16);
      hl32[hidx] = packed;                                        // plain copy (own L2)
      __hip_atomic_store(&hb32[hidx], packed,
                         __ATOMIC_RELAXED, __HIP_MEMORY_SCOPE_AGENT);  // sc1 copy
      int pos = (dir == 0) ? t : (m ? (len - 1 - t) : t);
      float ml = (float)len, ll = (float)llS[bl], al = (float)alS[bl];
      float p = (float)pos;
      float wl;
      if (p < ll) wl = 1.f - (ll - p) / ml;
      else if ((p >= ll + al) && (p < ml)) wl = 1.f - (p - ll - al + 1.f) / ml;
      else wl = 1.f;
      sv[z] = make_float2(h0N * wl, h1N * wl);
      sa[z] = &memv[((size_t)bglob * S_ + pos) * 600 + dir * 300 + u0 + ul0];
    }

    __builtin_amdgcn_fence(__ATOMIC_RELEASE, "workgroup");
    __syncthreads();  // vmcnt(0) drain: both h copies are ack'd
    if (tid == 0) {
      *(volatile u32*)&flagsP[g * 4] = (u32)(t + 1);               // plain flag (own L2)
      __hip_atomic_store(&flagsM[g * 4], (u32)(t + 1),
                         __ATOMIC_RELAXED, __HIP_MEMORY_SCOPE_AGENT);  // sc1 mirror
    }

    // deferred memv stores + next-step x prefetch — overlap the poll window
    #pragma unroll
    for (int z = 0; z < 2; ++z)
      if (sval[z]) *(float2*)sa[z] = sv[z];
    if (t + 1 < S_) {
      const u16* xr = memx + ((size_t)row * S_ + (t + 1)) * KPAD + quad * 8;
      #pragma unroll
      for (int kk = 0; kk < 10; ++kk) xv[kk] = *(const short8*)(xr + kk * 32);
    }
  }
}

// ---------------- K5: attention scores ----------------
__global__ __launch_bounds__(256) void score_kernel(const float* __restrict__ attW,
                                                    char* __restrict__ ws) {
  const int bid = blockIdx.x;
  const int b = bid >> 1, sh = bid & 1;
  const int tid = threadIdx.x, wv = tid >> 6, lane = tid & 63;
  __shared__ float aW[601];
  for (int i = tid; i < 601; i += 256) aW[i] = attW[i];
  const float* memv = (const float*)(ws + oMemV) + (size_t)b * S_ * 600;
  const float ml = (float)((const int*)(ws + oLens))[b];
  const float ll = (float)((const int*)(ws + oLens + 512))[b];
  const float al = (float)((const int*)(ws + oLens + 1024))[b];
  __syncthreads();
  float* scg = (float*)(ws + oSc) + b * S_;
  for (int s = sh * 128 + wv; s < sh * 128 + 128; s += 4) {
    const float* rowp = memv + (size_t)s * 600;
    float acc = 0.f;
    for (int d = lane; d < 600; d += 64) acc += rowp[d] * aW[d];
    for (int off = 32; off; off >>= 1) acc += __shfl_xor(acc, off);
    if (lane == 0) {
      float p = (float)s;
      bool inl = p < ll;
      bool inr = (p >= ll + al) && (p < ml);
      float u = inl ? (p - ll) : (inr ? (p - ll - al + 1.f) : 0.f);
      scg[s] = acc + u * aW[600];
    }
  }
}

// ---------------- K6: softmax + weighted sum -> i^T ----------------
__global__ __launch_bounds__(256) void attn_kernel(char* __restrict__ ws) {
  const int bid = blockIdx.x;
  const int b = bid >> 1, dh = bid & 1;
  const int tid = threadIdx.x, wv = tid >> 6, lane = tid & 63;
  __shared__ float alpha[256];
  __shared__ float red[8];
  const float* scg = (const float*)(ws + oSc) + b * S_;
  float v = scg[tid];
  float mx = v;
  for (int off = 32; off; off >>= 1) mx = fmaxf(mx, __shfl_xor(mx, off));
  if (lane == 0) red[wv] = mx;
  __syncthreads();
  mx = fmaxf(fmaxf(red[0], red[1]), fmaxf(red[2], red[3]));
  float e = __expf(v - mx);
  float sm = e;
  for (int off = 32; off; off >>= 1) sm += __shfl_xor(sm, off);
  if (lane == 0) red[4 + wv] = sm;
  __syncthreads();
  float tot = red[4] + red[5] + red[6] + red[7];
  alpha[tid] = e / tot;
  const float ml = (float)((const int*)(ws + oLens))[b];
  const float ll = (float)((const int*)(ws + oLens + 512))[b];
  const float al = (float)((const int*)(ws + oLens + 1024))[b];
  __syncthreads();
  const float* memv = (const float*)(ws + oMemV) + (size_t)b * S_ * 600;
  float* iT = (float*)(ws + oIT);
  const int d0 = dh * 301, d1 = dh ? 601 : 301;
  for (int d = d0 + tid; d < d1; d += 256) {
    float acc = 0.f;
    if (d < 600) {
      for (int s = 0; s < 256; ++s) acc += alpha[s] * memv[(size_t)s * 600 + d];
    } else {
      for (int s = 0; s < 256; ++s) {
        float p = (float)s;
        bool inl = p < ll;
        bool inr = (p >= ll + al) && (p < ml);
        float u = inl ? (p - ll) : (inr ? (p - ll - al + 1.f) : 0.f);
        acc += alpha[s] * u;
      }
    }
    iT[d * 128 + b] = acc;
  }
}

// ---------------- K7: GRU gi (once) ----------------
__global__ __launch_bounds__(256) void gi_kernel(const float* __restrict__ Wih,
                                                 const float* __restrict__ bih,
                                                 char* __restrict__ ws) {
  int idx = blockIdx.x * 256 + threadIdx.x;
  int r = idx >> 7, b = idx & 127;
  if (r >= 900) return;
  const float* iT = (const float*)(ws + oIT);
  const float* wr = Wih + (size_t)r * 601;
  float acc = bih[r];
  for (int d = 0; d < 601; ++d) acc += iT[d * 128 + b] * wr[d];
  ((float*)(ws + oGi))[r * 128 + b] = acc;
}

// ---------------- K8: GRU gh (per hop) ----------------
__global__ __launch_bounds__(256) void gh_kernel(const float* __restrict__ Whh,
                                                 const float* __restrict__ bhh,
                                                 char* __restrict__ ws) {
  int idx = blockIdx.x * 256 + threadIdx.x;
  int r = idx >> 7, b = idx & 127;
  if (r >= 900) return;
  const float* et = (const float*)(ws + oEt);
  const float* wr = Whh + (size_t)r * 300;
  float acc = bhh[r];
  for (int u = 0; u < 300; ++u) acc += et[u * 128 + b] * wr[u];
  ((float*)(ws + oGh))[r * 128 + b] = acc;
}

// ---------------- K9: GRU update (per hop) ----------------
__global__ __launch_bounds__(256) void up_kernel(char* __restrict__ ws) {
  int idx = blockIdx.x * 256 + threadIdx.x;
  int u = idx >> 7, b = idx & 127;
  if (u >= 300) return;
  const float* gi = (const float*)(ws + oGi);
  const float* gh = (const float*)(ws + oGh);
  float* et = (float*)(ws + oEt);
  float rr = sigm(gi[u * 128 + b] + gh[u * 128 + b]);
  float zz = sigm(gi[(300 + u) * 128 + b] + gh[(300 + u) * 128 + b]);
  float nn = tanh_f(gi[(600 + u) * 128 + b] + rr * gh[(600 + u) * 128 + b]);
  float old = et[u * 128 + b];
  et[u * 128 + b] = (1.f - zz) * nn + zz * old;
}

// ---------------- K10: dense head ----------------
__global__ __launch_bounds__(384) void dense_kernel(const float* __restrict__ dW,
                                                    const float* __restrict__ dB,
                                                    float* __restrict__ out,
                                                    const char* __restrict__ ws) {
  int tid = threadIdx.x;
  if (tid >= 384) return;
  int b = tid / 3, c = tid - 3 * (tid / 3);
  const float* et = (const float*)(ws + oEt);
  float acc = dB[c];
  const float* wr = dW + c * 300;
  for (int u = 0; u < 300; ++u) acc += et[u * 128 + b] * wr[u];
  out[b * 3 + c] = acc;
}

extern "C" void kernel_launch(void* const* d_in, const int* in_sizes, int n_in,
                              void* d_out, int out_size, void* d_ws, size_t ws_size,
                              hipStream_t stream) {
  const int* text = (const int*)d_in[0];
  const int* aspect = (const int*)d_in[1];
  const int* leftc = (const int*)d_in[2];
  const float* emb = (const float*)d_in[3];
  const float* WihF = (const float*)d_in[4];
  const float* WhhF = (const float*)d_in[5];
  const float* bihF = (const float*)d_in[6];
  const float* bhhF = (const float*)d_in[7];
  const float* WihB = (const float*)d_in[8];
  const float* WhhB = (const float*)d_in[9];
  const float* bihB = (const float*)d_in[10];
  const float* bhhB = (const float*)d_in[11];
  const float* attW = (const float*)d_in[12];
  const float* gruWih = (const float*)d_in[14];
  const float* gruWhh = (const float*)d_in[15];
  const float* gruBih = (const float*)d_in[16];
  const float* gruBhh = (const float*)d_in[17];
  const float* denseW = (const float*)d_in[18];
  const float* denseB = (const float*)d_in[19];
  float* out = (float*)d_out;
  char* ws = (char*)d_ws;
  if (ws_size < WS_NEED) return;

  init_kernel<<<67, 256, 0, stream>>>(text, aspect, leftc, ws);
  pack_kernel<<<6420, 256, 0, stream>>>(WihF, WhhF, bihF, bhhF, WihB, WhhB, bihB, bhhB, ws);
  gather_kernel<<<2 * B_ * S_, KPAD, 0, stream>>>(text, emb, ws);
  lstm_kernel<<<NBLK, 256, 0, stream>>>(ws);
  score_kernel<<<2 * B_, 256, 0, stream>>>(attW, ws);
  attn_kernel<<<2 * B_, 256, 0, stream>>>(ws);
  gi_kernel<<<450, 256, 0, stream>>>(gruWih, gruBih, ws);
  for (int h = 0; h < 3; ++h) {
    gh_kernel<<<450, 256, 0, stream>>>(gruWhh, gruBhh, ws);
    up_kernel<<<150, 256, 0, stream>>>(ws);
  }
  dense_kernel<<<1, 384, 0, stream>>>(denseW, denseB, out, ws);
}